// Round 26
// baseline (116.401 us; speedup 1.0000x reference)
//
#include <hip/hip_runtime.h>

#define DEV __device__ __forceinline__

typedef __bf16 bf16x8 __attribute__((ext_vector_type(8)));
typedef __bf16 bf16x4 __attribute__((ext_vector_type(4)));
typedef float f32x4 __attribute__((ext_vector_type(4)));
typedef unsigned u32x4 __attribute__((ext_vector_type(4)));
typedef unsigned short ushort_t;

static constexpr int EMBED = 1024;
static constexpr int NHEAD = 16;
static constexpr int HDIM  = 64;
static constexpr int S_    = 2048;
static constexpr float SCALE_L2E = 0.125f * 1.44269504088896340736f; // (1/sqrt(64))*log2(e)

DEV ushort_t f2bf(float f) {
  unsigned u = __builtin_bit_cast(unsigned, f);
  unsigned r = (u + 0x7fffu + ((u >> 16) & 1u)) >> 16;
  return (ushort_t)r;
}

// async global->LDS, 16B per lane; LDS dest is wave-uniform base + lane*16
#define GLOAD_LDS16(g, l)                                                   \
  __builtin_amdgcn_global_load_lds(                                         \
      (const __attribute__((address_space(1))) unsigned int*)(g),           \
      (__attribute__((address_space(3))) unsigned int*)(l), 16, 0, 0)

// explicit drain of global_load_lds before a publish barrier
#define DRAIN_VM() asm volatile("s_waitcnt vmcnt(0)" ::: "memory")

// ---------------------------------------------------------------------------
// fp32 -> bf16 conversion of x and the four weight matrices
// ---------------------------------------------------------------------------
__global__ __launch_bounds__(256) void convert_kernel(
    const float* __restrict__ x,
    const float* __restrict__ wq, const float* __restrict__ wk,
    const float* __restrict__ wv, const float* __restrict__ wo,
    ushort_t* __restrict__ xb, ushort_t* __restrict__ wqb,
    ushort_t* __restrict__ wkb, ushort_t* __restrict__ wvb,
    ushort_t* __restrict__ wob) {
  size_t i = ((size_t)blockIdx.x * blockDim.x + threadIdx.x) * 4;
  const float* src; ushort_t* dst; size_t off;
  if (i < 4194304u)      { src = x;  dst = xb;  off = i; }
  else if (i < 5242880u) { src = wq; dst = wqb; off = i - 4194304u; }
  else if (i < 6291456u) { src = wk; dst = wkb; off = i - 5242880u; }
  else if (i < 7340032u) { src = wv; dst = wvb; off = i - 6291456u; }
  else                   { src = wo; dst = wob; off = i - 7340032u; }
  float4 v = *(const float4*)(src + off);
  ushort4 o;
  o.x = f2bf(v.x); o.y = f2bf(v.y); o.z = f2bf(v.z); o.w = f2bf(v.w);
  *(ushort4*)(dst + off) = o;
}

// ---------------------------------------------------------------------------
// QKV GEMM, 1-D grid of 512 blocks:
//   bid <256 : PAIRED Q+K — one x-tile (A) feeds BOTH weight tiles:
//              Q = xb @ Wq^T (mask*SCALE_L2E), K = xb @ Wk^T (mask).
//              2x MFMA per staging barrier vs separate blocks.
//   else     : V^T (A=Wv, B=xb) -> [B,H,D,S], acc+bias (unchanged).
// 128x128 tiles, BK=64, 4 waves, single-buffer m97 structure.
// Per-output accumulation order identical to the unpaired version.
// ---------------------------------------------------------------------------
__global__ __launch_bounds__(256) void qkv_kernel(
    const ushort_t* __restrict__ xb, const ushort_t* __restrict__ wqb,
    const ushort_t* __restrict__ wkb, const ushort_t* __restrict__ wvb,
    const float* __restrict__ bq, const float* __restrict__ bk,
    const float* __restrict__ bv, const int* __restrict__ mask,
    ushort_t* __restrict__ qo, ushort_t* __restrict__ ko,
    ushort_t* __restrict__ vto) {
  __shared__ __align__(16) unsigned char ldsA[16384];
  __shared__ __align__(16) unsigned char ldsB0[16384];
  __shared__ __align__(16) unsigned char ldsB1[16384];
  __shared__ float maskf[2][128];

  const int bid  = blockIdx.x;
  const int tid  = threadIdx.x;
  const int lane = tid & 63;
  const int w    = tid >> 6;
  const int wm   = (w >> 1) * 64;
  const int wn   = (w & 1) * 64;
  const int rl   = lane & 15;
  const int kg   = lane >> 4;

  if (bid < 256) {
    // ---------------- paired Q+K ----------------
    const int t   = bid;
    const int ar0 = (t & 31) * 128;   // x rows
    const int br0 = (t >> 5) * 128;   // weight rows (same heads for Q and K)

    {
      int hl = tid >> 7, sl = tid & 127;
      int m = ar0 + sl;
      int b = m >> 11, s = m & 2047;
      int h = (br0 >> 6) + hl;
      maskf[hl][sl] = (float)mask[((size_t)b * NHEAD + h) * S_ + s];
    }

    f32x4 accQ[4][4], accK[4][4];
#pragma unroll
    for (int i = 0; i < 4; ++i)
#pragma unroll
      for (int j = 0; j < 4; ++j) {
        accQ[i][j] = f32x4{0.f, 0.f, 0.f, 0.f};
        accK[i][j] = f32x4{0.f, 0.f, 0.f, 0.f};
      }

    auto STAGE = [&](int kt) {
      const int k0 = kt * 64;
#pragma unroll
      for (int s = 0; s < 12; ++s) {
        const int Lb = (s & 3) * 256 + w * 64;   // wave-uniform
        const int L = Lb + lane;
        const int row = L >> 3;
        const int gu = (L & 7) ^ (row & 7);
        if (s < 4) {
          GLOAD_LDS16(xb + (size_t)(ar0 + row) * EMBED + k0 + gu * 8, &ldsA[Lb * 16]);
        } else if (s < 8) {
          GLOAD_LDS16(wqb + (size_t)(br0 + row) * EMBED + k0 + gu * 8, &ldsB0[Lb * 16]);
        } else {
          GLOAD_LDS16(wkb + (size_t)(br0 + row) * EMBED + k0 + gu * 8, &ldsB1[Lb * 16]);
        }
      }
    };

    for (int kt = 0; kt < 16; ++kt) {
      if (kt) __syncthreads();
      STAGE(kt);
      DRAIN_VM();
      __syncthreads();
#pragma unroll
      for (int kk = 0; kk < 2; ++kk) {
        bf16x8 af[4], bq4[4], bk4[4];
#pragma unroll
        for (int mb = 0; mb < 4; ++mb) {
          const int row = wm + mb * 16 + rl;
          const int off = (kk * 64 + kg * 16) ^ ((row & 7) << 4);
          af[mb] = *(const bf16x8*)(ldsA + row * 128 + off);
        }
#pragma unroll
        for (int nb = 0; nb < 4; ++nb) {
          const int row = wn + nb * 16 + rl;
          const int off = (kk * 64 + kg * 16) ^ ((row & 7) << 4);
          bq4[nb] = *(const bf16x8*)(ldsB0 + row * 128 + off);
          bk4[nb] = *(const bf16x8*)(ldsB1 + row * 128 + off);
        }
#pragma unroll
        for (int mb = 0; mb < 4; ++mb)
#pragma unroll
          for (int nb = 0; nb < 4; ++nb) {
            accQ[mb][nb] = __builtin_amdgcn_mfma_f32_16x16x32_bf16(
                af[mb], bq4[nb], accQ[mb][nb], 0, 0, 0);
            accK[mb][nb] = __builtin_amdgcn_mfma_f32_16x16x32_bf16(
                af[mb], bk4[nb], accK[mb][nb], 0, 0, 0);
          }
      }
    }

    // epilogue — D layout: row(A idx)=(lane>>4)*4+r, col(B idx)=lane&15
#pragma unroll
    for (int mb = 0; mb < 4; ++mb)
#pragma unroll
      for (int nb = 0; nb < 4; ++nb)
#pragma unroll
        for (int r = 0; r < 4; ++r) {
          int row_l = wm + mb * 16 + kg * 4 + r;
          int col_l = wn + nb * 16 + rl;
          int m = ar0 + row_l, n = br0 + col_l;
          float mk = maskf[col_l >> 6][row_l];
          int b = m >> 11, s = m & 2047, h = n >> 6, d = n & 63;
          size_t oidx = (((size_t)(b * NHEAD + h)) * S_ + s) * HDIM + d;
          qo[oidx] = f2bf((accQ[mb][nb][r] + bq[n]) * mk * SCALE_L2E);
          ko[oidx] = f2bf((accK[mb][nb][r] + bk[n]) * mk);
        }
  } else {
    // ---------------- V^T (unchanged math) ----------------
    const int t   = bid - 256;
    const int ar0 = (t & 7) * 128;    // weight rows
    const int br0 = (t >> 3) * 128;   // x rows

    f32x4 acc[4][4];
#pragma unroll
    for (int i = 0; i < 4; ++i)
#pragma unroll
      for (int j = 0; j < 4; ++j) acc[i][j] = f32x4{0.f, 0.f, 0.f, 0.f};

    auto STAGE = [&](int kt) {
      const int k0 = kt * 64;
#pragma unroll
      for (int s = 0; s < 8; ++s) {
        const int Lb = (s & 3) * 256 + w * 64;   // wave-uniform
        const int L = Lb + lane;
        const int row = L >> 3;
        const int gu = (L & 7) ^ (row & 7);
        if (s < 4) {
          GLOAD_LDS16(wvb + (size_t)(ar0 + row) * EMBED + k0 + gu * 8, &ldsA[Lb * 16]);
        } else {
          GLOAD_LDS16(xb + (size_t)(br0 + row) * EMBED + k0 + gu * 8, &ldsB0[Lb * 16]);
        }
      }
    };

    for (int kt = 0; kt < 16; ++kt) {
      if (kt) __syncthreads();
      STAGE(kt);
      DRAIN_VM();
      __syncthreads();
#pragma unroll
      for (int kk = 0; kk < 2; ++kk) {
        bf16x8 af[4], bfr[4];
#pragma unroll
        for (int mb = 0; mb < 4; ++mb) {
          const int row = wm + mb * 16 + rl;
          const int off = (kk * 64 + kg * 16) ^ ((row & 7) << 4);
          af[mb] = *(const bf16x8*)(ldsA + row * 128 + off);
        }
#pragma unroll
        for (int nb = 0; nb < 4; ++nb) {
          const int row = wn + nb * 16 + rl;
          const int off = (kk * 64 + kg * 16) ^ ((row & 7) << 4);
          bfr[nb] = *(const bf16x8*)(ldsB0 + row * 128 + off);
        }
#pragma unroll
        for (int mb = 0; mb < 4; ++mb)
#pragma unroll
          for (int nb = 0; nb < 4; ++nb)
            acc[mb][nb] = __builtin_amdgcn_mfma_f32_16x16x32_bf16(
                af[mb], bfr[nb], acc[mb][nb], 0, 0, 0);
      }
    }

#pragma unroll
    for (int mb = 0; mb < 4; ++mb)
#pragma unroll
      for (int nb = 0; nb < 4; ++nb)
#pragma unroll
        for (int r = 0; r < 4; ++r) {
          int row_l = wm + mb * 16 + kg * 4 + r;
          int col_l = wn + nb * 16 + rl;
          int n = ar0 + row_l, m = br0 + col_l;
          float v = acc[mb][nb][r] + bv[n];
          int b = m >> 11, s = m & 2047, h = n >> 6, d = n & 63;
          vto[(((size_t)(b * NHEAD + h)) * HDIM + d) * S_ + s] = f2bf(v);
        }
  }
}

// ---------------------------------------------------------------------------
// O projection GEMM: out[m][n] = aob[m][:] . Wo[n][:] + bo[n]  (fp32 out)
// R12-green single-buffer m97 structure.
// ---------------------------------------------------------------------------
__global__ __launch_bounds__(256) void gemm_o_kernel(
    const ushort_t* __restrict__ A, const ushort_t* __restrict__ Bm,
    const float* __restrict__ bias, float* __restrict__ outp) {
  __shared__ __align__(16) unsigned char ldsA[16384];
  __shared__ __align__(16) unsigned char ldsB[16384];

  const int tid  = threadIdx.x;
  const int lane = tid & 63;
  const int w    = tid >> 6;
  const int ar0  = blockIdx.x * 128;
  const int br0  = blockIdx.y * 128;
  const int wm   = (w >> 1) * 64;
  const int wn   = (w & 1) * 64;
  const int rl   = lane & 15;
  const int kg   = lane >> 4;

  f32x4 acc[4][4];
#pragma unroll
  for (int i = 0; i < 4; ++i)
#pragma unroll
    for (int j = 0; j < 4; ++j) acc[i][j] = f32x4{0.f, 0.f, 0.f, 0.f};

  auto STAGE = [&](int kt) {
    const int k0 = kt * 64;
#pragma unroll
    for (int s = 0; s < 8; ++s) {
      const int basev = s * 256 + w * 64;
      const int Lb = basev & 1023;
      const int L = Lb + lane;
      const int row = L >> 3;
      const int gu = (L & 7) ^ (row & 7);
      if (s < 4) {
        GLOAD_LDS16(A + (size_t)(ar0 + row) * EMBED + k0 + gu * 8, &ldsA[Lb * 16]);
      } else {
        GLOAD_LDS16(Bm + (size_t)(br0 + row) * EMBED + k0 + gu * 8, &ldsB[Lb * 16]);
      }
    }
  };

  for (int kt = 0; kt < 16; ++kt) {
    if (kt) __syncthreads();
    STAGE(kt);
    DRAIN_VM();
    __syncthreads();
#pragma unroll
    for (int kk = 0; kk < 2; ++kk) {
      bf16x8 af[4], bfr[4];
#pragma unroll
      for (int mb = 0; mb < 4; ++mb) {
        const int row = wm + mb * 16 + rl;
        const int off = (kk * 64 + kg * 16) ^ ((row & 7) << 4);
        af[mb] = *(const bf16x8*)(ldsA + row * 128 + off);
      }
#pragma unroll
      for (int nb = 0; nb < 4; ++nb) {
        const int row = wn + nb * 16 + rl;
        const int off = (kk * 64 + kg * 16) ^ ((row & 7) << 4);
        bfr[nb] = *(const bf16x8*)(ldsB + row * 128 + off);
      }
#pragma unroll
      for (int mb = 0; mb < 4; ++mb)
#pragma unroll
        for (int nb = 0; nb < 4; ++nb)
          acc[mb][nb] = __builtin_amdgcn_mfma_f32_16x16x32_bf16(
              af[mb], bfr[nb], acc[mb][nb], 0, 0, 0);
    }
  }

#pragma unroll
  for (int mb = 0; mb < 4; ++mb)
#pragma unroll
    for (int nb = 0; nb < 4; ++nb)
#pragma unroll
      for (int r = 0; r < 4; ++r) {
        int m = ar0 + wm + mb * 16 + kg * 4 + r;
        int n = br0 + wn + nb * 16 + rl;
        outp[(size_t)m * EMBED + n] = acc[mb][nb][r] + bias[n];
      }
}

// ---------------------------------------------------------------------------
// Flash attention, swapped-QK^T, fixed-exponent softmax — 2-TILE UNROLL
// (intra-wave ILP): per iteration process tiles A=kt, B=kt+1:
//   QK_A; QK_B; SM_A-writes | fence | {P_A read, l_A, PV_A  ||  SM_B VALU}
//   | fence | P_B read, l_B, PV_B
// so PV_A MFMAs co-issue with SM_B exp2 (separate pipes, same wave).
// 4 KV slots (tile kt -> slot kt&3), 2-tiles-ahead prefetch, counted
// vmcnt(4) with a full iteration of slack; raw s_barrier (2 per 2 tiles).
// P buffer reused A->B per wave (may-alias ordering + in-order DS).
// 8 waves x 16 q; XCD-resident decode; s_setprio around MFMA clusters.
// LDS: K 4x8KB + V 4x8KB + P 8x2KB = 80KB -> 2 blocks/CU.  (R23-green)
// ---------------------------------------------------------------------------
__global__ __launch_bounds__(512) void attn_kernel(
    const ushort_t* __restrict__ qp, const ushort_t* __restrict__ kp,
    const ushort_t* __restrict__ vtp, ushort_t* __restrict__ ao) {
  __shared__ __align__(16) unsigned char ldsK[4][8192];
  __shared__ __align__(16) unsigned char ldsV[4][8192];
  __shared__ __align__(16) unsigned char ldsP[8][2048];

  const int bid  = blockIdx.x;
  const int bh   = (bid & 7) * 4 + (bid >> 7); // XCD-resident head slice
  const int qt   = (bid >> 3) & 15;
  const int tid  = threadIdx.x;
  const int lane = tid & 63;
  const int w    = tid >> 6;                  // 0..7
  const int q0   = qt * 128 + w * 16;         // wave's q base (16 rows)
  const int rl   = lane & 15;
  const int kg   = lane >> 4;
  const int pswz = (rl & 7) << 4;

  const bf16x8 ones = __builtin_bit_cast(bf16x8,
      u32x4{0x3F803F80u, 0x3F803F80u, 0x3F803F80u, 0x3F803F80u});

  // Q fragments (B-operand): lane (rl,kg) holds Q[q=rl][d=kk*32+kg*8..+8]
  bf16x8 qa[2];
#pragma unroll
  for (int kk = 0; kk < 2; ++kk)
    qa[kk] = *(const bf16x8*)(qp + ((size_t)bh * S_ + q0 + rl) * HDIM +
                              kk * 32 + kg * 8);

  f32x4 o_acc[4];
  f32x4 o_l = f32x4{0.f, 0.f, 0.f, 0.f};
#pragma unroll
  for (int nb = 0; nb < 4; ++nb) o_acc[nb] = f32x4{0.f, 0.f, 0.f, 0.f};

  unsigned char* pb = ldsP[w];

  // stage KV tile kt into slot: 512 K units + 512 V units, 2 insts/thread
  auto STAGE = [&](int kt, int slot) {
#pragma unroll
    for (int s = 0; s < 2; ++s) {
      const int Lb = w * 64;                  // wave-uniform, 8 waves x 64
      const int L = Lb + lane;
      const int row = L >> 3;
      const int gu = (L & 7) ^ (row & 7);
      if (s == 0) {
        GLOAD_LDS16(kp + ((size_t)bh * S_ + (size_t)kt * 64 + row) * HDIM + gu * 8,
                    &ldsK[slot][L * 16]);
      } else {
        GLOAD_LDS16(vtp + ((size_t)bh * HDIM + row) * S_ + (size_t)kt * 64 + gu * 8,
                    &ldsV[slot][L * 16]);
      }
    }
  };

  // per-tile pieces (static indexing; called twice per iteration)
  auto QK = [&](int slot, f32x4 sa[4]) {
#pragma unroll
    for (int nb = 0; nb < 4; ++nb) {
      const int row = nb * 16 + rl;
#pragma unroll
      for (int kk = 0; kk < 2; ++kk) {
        bf16x8 kf = *(const bf16x8*)(ldsK[slot] + row * 128 +
                                     ((kk * 64 + kg * 16) ^ ((row & 7) << 4)));
        sa[nb] = __builtin_amdgcn_mfma_f32_16x16x32_bf16(kf, qa[kk], sa[nb], 0, 0, 0);
      }
    }
  };
  auto SMW = [&](const f32x4 sa[4]) {          // exp2 -> bf16 -> P writes
#pragma unroll
    for (int nb = 0; nb < 4; ++nb) {
      bf16x4 pk4;
#pragma unroll
      for (int r = 0; r < 4; ++r)
        pk4[r] = (__bf16)__builtin_amdgcn_exp2f(sa[nb][r]);
      *(bf16x4*)(pb + rl * 128 + ((nb * 32 + kg * 8) ^ pswz)) = pk4;
    }
  };
  auto PVL = [&](int slot) {                   // P read, l, PV
    bf16x8 pa[2];
#pragma unroll
    for (int kk = 0; kk < 2; ++kk)
      pa[kk] = *(const bf16x8*)(pb + rl * 128 + ((kk * 64 + kg * 16) ^ pswz));
    o_l = __builtin_amdgcn_mfma_f32_16x16x32_bf16(pa[0], ones, o_l, 0, 0, 0);
    o_l = __builtin_amdgcn_mfma_f32_16x16x32_bf16(pa[1], ones, o_l, 0, 0, 0);
#pragma unroll
    for (int nb = 0; nb < 4; ++nb) {
      const int row = nb * 16 + rl;
#pragma unroll
      for (int kk = 0; kk < 2; ++kk) {
        bf16x8 vb = *(const bf16x8*)(ldsV[slot] + row * 128 +
                                     ((kk * 64 + kg * 16) ^ ((row & 7) << 4)));
        o_acc[nb] = __builtin_amdgcn_mfma_f32_16x16x32_bf16(pa[kk], vb, o_acc[nb], 0, 0, 0);
      }
    }
  };

  STAGE(0, 0); STAGE(1, 1); STAGE(2, 2); STAGE(3, 3);
  asm volatile("s_waitcnt vmcnt(4) lgkmcnt(0)" ::: "memory"); // tiles 0,1 landed
  __builtin_amdgcn_s_barrier();

  for (int kt = 0; kt < 32; kt += 2) {
    const int s0 = kt & 3, s1 = (kt + 1) & 3;

    f32x4 saA[4], saB[4];
#pragma unroll
    for (int nb = 0; nb < 4; ++nb) { saA[nb] = f32x4{0.f,0.f,0.f,0.f}; saB[nb] = f32x4{0.f,0.f,0.f,0.f}; }

    __builtin_amdgcn_s_setprio(1);
    QK(s0, saA);
    QK(s1, saB);
    __builtin_amdgcn_s_setprio(0);

    SMW(saA);
    asm volatile("s_waitcnt lgkmcnt(0)" ::: "memory");
    __builtin_amdgcn_sched_barrier(0);

    // region: PV_A MFMAs interleave with SM_B VALU (independent, same wave)
    __builtin_amdgcn_s_setprio(1);
    PVL(s0);
    __builtin_amdgcn_s_setprio(0);
    SMW(saB);
    asm volatile("s_waitcnt lgkmcnt(0)" ::: "memory");
    __builtin_amdgcn_sched_barrier(0);

    __builtin_amdgcn_s_setprio(1);
    PVL(s1);
    __builtin_amdgcn_s_setprio(0);

    // publish: all waves done reading slots s0,s1; restage them 2 ahead
    __builtin_amdgcn_s_barrier();
    if (kt + 4 < 32) {
      STAGE(kt + 4, s0); STAGE(kt + 5, s1);
      asm volatile("s_waitcnt vmcnt(4) lgkmcnt(0)" ::: "memory"); // kt+2,kt+3 landed
    } else {
      asm volatile("s_waitcnt vmcnt(0) lgkmcnt(0)" ::: "memory");
    }
    __builtin_amdgcn_s_barrier();
  }

  // epilogue: O[q=kg*4+r][d=nb*16+rl] / l[q]; o_l aligned with o_acc
  const int b = bh >> 4, h = bh & 15;
#pragma unroll
  for (int r = 0; r < 4; ++r) {
    float linv = 1.0f / o_l[r];
    const int row = q0 + kg * 4 + r;
#pragma unroll
    for (int nb = 0; nb < 4; ++nb) {
      float v = o_acc[nb][r] * linv;
      ao[((size_t)b * S_ + row) * EMBED + h * HDIM + nb * 16 + rl] = f2bf(v);
    }
  }
}

// ---------------------------------------------------------------------------
extern "C" void kernel_launch(void* const* d_in, const int* in_sizes, int n_in,
                              void* d_out, int out_size, void* d_ws, size_t ws_size,
                              hipStream_t stream) {
  const float* x    = (const float*)d_in[0];
  const int*   mask = (const int*)d_in[1];
  const float* Wq   = (const float*)d_in[2];
  const float* bq   = (const float*)d_in[3];
  const float* Wk   = (const float*)d_in[4];
  const float* bk   = (const float*)d_in[5];
  const float* Wv   = (const float*)d_in[6];
  const float* bv   = (const float*)d_in[7];
  const float* Wo   = (const float*)d_in[8];
  const float* bo   = (const float*)d_in[9];

  char* ws = (char*)d_ws;
  ushort_t* xb  = (ushort_t*)(ws);
  ushort_t* wqb = (ushort_t*)(ws + 8388608);
  ushort_t* wkb = (ushort_t*)(ws + 10485760);
  ushort_t* wvb = (ushort_t*)(ws + 12582912);
  ushort_t* wob = (ushort_t*)(ws + 14680064);
  ushort_t* qb  = (ushort_t*)(ws + 16777216);
  ushort_t* kb  = (ushort_t*)(ws + 25165824);
  ushort_t* vtb = (ushort_t*)(ws + 33554432);
  ushort_t* aob = (ushort_t*)(ws + 41943040);

  hipLaunchKernelGGL(convert_kernel, dim3(8192), dim3(256), 0, stream,
                     x, Wq, Wk, Wv, Wo, xb, wqb, wkb, wvb, wob);
  hipLaunchKernelGGL(qkv_kernel, dim3(512), dim3(256), 0, stream,
                     xb, wqb, wkb, wvb, bq, bk, bv, mask, qb, kb, vtb);
  hipLaunchKernelGGL(attn_kernel, dim3(512), dim3(512), 0, stream,
                     qb, kb, vtb, aob);
  hipLaunchKernelGGL(gemm_o_kernel, dim3(32, 8), dim3(256), 0, stream,
                     aob, wob, bo, (float*)d_out);
}

// Round 27
// 111.397 us; speedup vs baseline: 1.0449x; 1.0449x over previous
//
#include <hip/hip_runtime.h>

#define DEV __device__ __forceinline__

typedef __bf16 bf16x8 __attribute__((ext_vector_type(8)));
typedef __bf16 bf16x4 __attribute__((ext_vector_type(4)));
typedef float f32x4 __attribute__((ext_vector_type(4)));
typedef unsigned u32x4 __attribute__((ext_vector_type(4)));
typedef unsigned short ushort_t;

static constexpr int EMBED = 1024;
static constexpr int NHEAD = 16;
static constexpr int HDIM  = 64;
static constexpr int S_    = 2048;
static constexpr float SCALE_L2E = 0.125f * 1.44269504088896340736f; // (1/sqrt(64))*log2(e)

DEV ushort_t f2bf(float f) {
  unsigned u = __builtin_bit_cast(unsigned, f);
  unsigned r = (u + 0x7fffu + ((u >> 16) & 1u)) >> 16;
  return (ushort_t)r;
}

// async global->LDS, 16B per lane; LDS dest is wave-uniform base + lane*16
#define GLOAD_LDS16(g, l)                                                   \
  __builtin_amdgcn_global_load_lds(                                         \
      (const __attribute__((address_space(1))) unsigned int*)(g),           \
      (__attribute__((address_space(3))) unsigned int*)(l), 16, 0, 0)

// explicit drain of global_load_lds before a publish barrier
#define DRAIN_VM() asm volatile("s_waitcnt vmcnt(0)" ::: "memory")

// ---------------------------------------------------------------------------
// fp32 -> bf16 conversion of x and the four weight matrices
// ---------------------------------------------------------------------------
__global__ __launch_bounds__(256) void convert_kernel(
    const float* __restrict__ x,
    const float* __restrict__ wq, const float* __restrict__ wk,
    const float* __restrict__ wv, const float* __restrict__ wo,
    ushort_t* __restrict__ xb, ushort_t* __restrict__ wqb,
    ushort_t* __restrict__ wkb, ushort_t* __restrict__ wvb,
    ushort_t* __restrict__ wob) {
  size_t i = ((size_t)blockIdx.x * blockDim.x + threadIdx.x) * 4;
  const float* src; ushort_t* dst; size_t off;
  if (i < 4194304u)      { src = x;  dst = xb;  off = i; }
  else if (i < 5242880u) { src = wq; dst = wqb; off = i - 4194304u; }
  else if (i < 6291456u) { src = wk; dst = wkb; off = i - 5242880u; }
  else if (i < 7340032u) { src = wv; dst = wvb; off = i - 6291456u; }
  else                   { src = wo; dst = wob; off = i - 7340032u; }
  float4 v = *(const float4*)(src + off);
  ushort4 o;
  o.x = f2bf(v.x); o.y = f2bf(v.y); o.z = f2bf(v.z); o.w = f2bf(v.w);
  *(ushort4*)(dst + off) = o;
}

// ---------------------------------------------------------------------------
// Merged QKV GEMM, 1-D grid of 768 blocks (R12-green single-buffer m97):
//   bid <256 : Q = xb @ Wq^T  -> [B,H,S,D], (acc+bias)*mask*SCALE_L2E
//   bid <512 : K = xb @ Wk^T  -> [B,H,S,D], (acc+bias)*mask
//   else     : V^T (A=Wv, B=xb) -> [B,H,D,S], acc+bias
// ---------------------------------------------------------------------------
__global__ __launch_bounds__(256) void qkv_kernel(
    const ushort_t* __restrict__ xb, const ushort_t* __restrict__ wqb,
    const ushort_t* __restrict__ wkb, const ushort_t* __restrict__ wvb,
    const float* __restrict__ bq, const float* __restrict__ bk,
    const float* __restrict__ bv, const int* __restrict__ mask,
    ushort_t* __restrict__ qo, ushort_t* __restrict__ ko,
    ushort_t* __restrict__ vto) {
  __shared__ __align__(16) unsigned char ldsA[16384];
  __shared__ __align__(16) unsigned char ldsB[16384];
  __shared__ float maskf[2][128];

  const int bid  = blockIdx.x;
  const int tid  = threadIdx.x;
  const int lane = tid & 63;
  const int w    = tid >> 6;
  const int wm   = (w >> 1) * 64;
  const int wn   = (w & 1) * 64;
  const int rl   = lane & 15;
  const int kg   = lane >> 4;

  int mode, ar0, br0;
  const ushort_t *A, *Bm;
  const float* bias;
  if (bid < 512) {
    mode = bid >> 8;                 // 0=Q, 1=K
    int t = bid & 255;
    ar0 = (t & 31) * 128;            // x rows
    br0 = (t >> 5) * 128;            // weight rows
    A = xb; Bm = mode ? wkb : wqb; bias = mode ? bk : bq;
  } else {
    mode = 2;
    int t = bid - 512;
    ar0 = (t & 7) * 128;             // weight rows
    br0 = (t >> 3) * 128;            // x rows
    A = wvb; Bm = xb; bias = bv;
  }

  if (mode < 2) {
    int hl = tid >> 7, sl = tid & 127;
    int m = ar0 + sl;
    int b = m >> 11, s = m & 2047;
    int h = (br0 >> 6) + hl;
    maskf[hl][sl] = (float)mask[((size_t)b * NHEAD + h) * S_ + s];
  }

  f32x4 acc[4][4];
#pragma unroll
  for (int i = 0; i < 4; ++i)
#pragma unroll
    for (int j = 0; j < 4; ++j) acc[i][j] = f32x4{0.f, 0.f, 0.f, 0.f};

  auto STAGE = [&](int kt) {
    const int k0 = kt * 64;
#pragma unroll
    for (int s = 0; s < 8; ++s) {
      const int basev = s * 256 + w * 64;   // wave-uniform
      const int Lb = basev & 1023;
      const int L = Lb + lane;
      const int row = L >> 3;
      const int gu = (L & 7) ^ (row & 7);
      if (s < 4) {
        GLOAD_LDS16(A + (size_t)(ar0 + row) * EMBED + k0 + gu * 8, &ldsA[Lb * 16]);
      } else {
        GLOAD_LDS16(Bm + (size_t)(br0 + row) * EMBED + k0 + gu * 8, &ldsB[Lb * 16]);
      }
    }
  };

  for (int kt = 0; kt < 16; ++kt) {
    if (kt) __syncthreads();          // all waves done reading previous tile
    STAGE(kt);
    DRAIN_VM();                       // my loads landed
    __syncthreads();                  // everyone's loads landed
#pragma unroll
    for (int kk = 0; kk < 2; ++kk) {
      bf16x8 af[4], bfr[4];
#pragma unroll
      for (int mb = 0; mb < 4; ++mb) {
        const int row = wm + mb * 16 + rl;
        const int off = (kk * 64 + kg * 16) ^ ((row & 7) << 4);
        af[mb] = *(const bf16x8*)(ldsA + row * 128 + off);
      }
#pragma unroll
      for (int nb = 0; nb < 4; ++nb) {
        const int row = wn + nb * 16 + rl;
        const int off = (kk * 64 + kg * 16) ^ ((row & 7) << 4);
        bfr[nb] = *(const bf16x8*)(ldsB + row * 128 + off);
      }
#pragma unroll
      for (int mb = 0; mb < 4; ++mb)
#pragma unroll
        for (int nb = 0; nb < 4; ++nb)
          acc[mb][nb] = __builtin_amdgcn_mfma_f32_16x16x32_bf16(
              af[mb], bfr[nb], acc[mb][nb], 0, 0, 0);
    }
  }

  // epilogue — D layout: row(A idx)=(lane>>4)*4+r, col(B idx)=lane&15
#pragma unroll
  for (int mb = 0; mb < 4; ++mb)
#pragma unroll
    for (int nb = 0; nb < 4; ++nb)
#pragma unroll
      for (int r = 0; r < 4; ++r) {
        int row_l = wm + mb * 16 + kg * 4 + r;
        int col_l = wn + nb * 16 + rl;
        float v = acc[mb][nb][r];
        if (mode < 2) {
          int m = ar0 + row_l, n = br0 + col_l;
          v = (v + bias[n]) * maskf[col_l >> 6][row_l];
          if (mode == 0) v *= SCALE_L2E;
          int b = m >> 11, s = m & 2047, h = n >> 6, d = n & 63;
          ushort_t* o = mode ? ko : qo;
          o[(((size_t)(b * NHEAD + h)) * S_ + s) * HDIM + d] = f2bf(v);
        } else {
          int n = ar0 + row_l, m = br0 + col_l;
          v += bias[n];
          int b = m >> 11, s = m & 2047, h = n >> 6, d = n & 63;
          vto[(((size_t)(b * NHEAD + h)) * HDIM + d) * S_ + s] = f2bf(v);
        }
      }
}

// ---------------------------------------------------------------------------
// O projection GEMM: out[m][n] = aob[m][:] . Wo[n][:] + bo[n]  (fp32 out)
// R12-green single-buffer m97 structure.
// ---------------------------------------------------------------------------
__global__ __launch_bounds__(256) void gemm_o_kernel(
    const ushort_t* __restrict__ A, const ushort_t* __restrict__ Bm,
    const float* __restrict__ bias, float* __restrict__ outp) {
  __shared__ __align__(16) unsigned char ldsA[16384];
  __shared__ __align__(16) unsigned char ldsB[16384];

  const int tid  = threadIdx.x;
  const int lane = tid & 63;
  const int w    = tid >> 6;
  const int ar0  = blockIdx.x * 128;
  const int br0  = blockIdx.y * 128;
  const int wm   = (w >> 1) * 64;
  const int wn   = (w & 1) * 64;
  const int rl   = lane & 15;
  const int kg   = lane >> 4;

  f32x4 acc[4][4];
#pragma unroll
  for (int i = 0; i < 4; ++i)
#pragma unroll
    for (int j = 0; j < 4; ++j) acc[i][j] = f32x4{0.f, 0.f, 0.f, 0.f};

  auto STAGE = [&](int kt) {
    const int k0 = kt * 64;
#pragma unroll
    for (int s = 0; s < 8; ++s) {
      const int basev = s * 256 + w * 64;
      const int Lb = basev & 1023;
      const int L = Lb + lane;
      const int row = L >> 3;
      const int gu = (L & 7) ^ (row & 7);
      if (s < 4) {
        GLOAD_LDS16(A + (size_t)(ar0 + row) * EMBED + k0 + gu * 8, &ldsA[Lb * 16]);
      } else {
        GLOAD_LDS16(Bm + (size_t)(br0 + row) * EMBED + k0 + gu * 8, &ldsB[Lb * 16]);
      }
    }
  };

  for (int kt = 0; kt < 16; ++kt) {
    if (kt) __syncthreads();
    STAGE(kt);
    DRAIN_VM();
    __syncthreads();
#pragma unroll
    for (int kk = 0; kk < 2; ++kk) {
      bf16x8 af[4], bfr[4];
#pragma unroll
      for (int mb = 0; mb < 4; ++mb) {
        const int row = wm + mb * 16 + rl;
        const int off = (kk * 64 + kg * 16) ^ ((row & 7) << 4);
        af[mb] = *(const bf16x8*)(ldsA + row * 128 + off);
      }
#pragma unroll
      for (int nb = 0; nb < 4; ++nb) {
        const int row = wn + nb * 16 + rl;
        const int off = (kk * 64 + kg * 16) ^ ((row & 7) << 4);
        bfr[nb] = *(const bf16x8*)(ldsB + row * 128 + off);
      }
#pragma unroll
      for (int mb = 0; mb < 4; ++mb)
#pragma unroll
        for (int nb = 0; nb < 4; ++nb)
          acc[mb][nb] = __builtin_amdgcn_mfma_f32_16x16x32_bf16(
              af[mb], bfr[nb], acc[mb][nb], 0, 0, 0);
    }
  }

#pragma unroll
  for (int mb = 0; mb < 4; ++mb)
#pragma unroll
    for (int nb = 0; nb < 4; ++nb)
#pragma unroll
      for (int r = 0; r < 4; ++r) {
        int m = ar0 + wm + mb * 16 + kg * 4 + r;
        int n = br0 + wn + nb * 16 + rl;
        outp[(size_t)m * EMBED + n] = acc[mb][nb][r] + bias[n];
      }
}

// ---------------------------------------------------------------------------
// Flash attention, swapped-QK^T, fixed-exponent softmax — 2-TILE UNROLL
// (intra-wave ILP): per iteration process tiles A=kt, B=kt+1:
//   QK_A; QK_B; SM_A-writes | fence | {P_A read, l_A, PV_A  ||  SM_B VALU}
//   | fence | P_B read, l_B, PV_B
// so PV_A MFMAs co-issue with SM_B exp2 (separate pipes, same wave).
// 4 KV slots (tile kt -> slot kt&3), 2-tiles-ahead prefetch, counted
// vmcnt(4) with a full iteration of slack; raw s_barrier (2 per 2 tiles).
// P buffer reused A->B per wave (may-alias ordering + in-order DS).
// 8 waves x 16 q; XCD-resident decode; s_setprio around MFMA clusters.
// LDS: K 4x8KB + V 4x8KB + P 8x2KB = 80KB -> 2 blocks/CU.  (R23/R25-green)
// ---------------------------------------------------------------------------
__global__ __launch_bounds__(512) void attn_kernel(
    const ushort_t* __restrict__ qp, const ushort_t* __restrict__ kp,
    const ushort_t* __restrict__ vtp, ushort_t* __restrict__ ao) {
  __shared__ __align__(16) unsigned char ldsK[4][8192];
  __shared__ __align__(16) unsigned char ldsV[4][8192];
  __shared__ __align__(16) unsigned char ldsP[8][2048];

  const int bid  = blockIdx.x;
  const int bh   = (bid & 7) * 4 + (bid >> 7); // XCD-resident head slice
  const int qt   = (bid >> 3) & 15;
  const int tid  = threadIdx.x;
  const int lane = tid & 63;
  const int w    = tid >> 6;                  // 0..7
  const int q0   = qt * 128 + w * 16;         // wave's q base (16 rows)
  const int rl   = lane & 15;
  const int kg   = lane >> 4;
  const int pswz = (rl & 7) << 4;

  const bf16x8 ones = __builtin_bit_cast(bf16x8,
      u32x4{0x3F803F80u, 0x3F803F80u, 0x3F803F80u, 0x3F803F80u});

  // Q fragments (B-operand): lane (rl,kg) holds Q[q=rl][d=kk*32+kg*8..+8]
  bf16x8 qa[2];
#pragma unroll
  for (int kk = 0; kk < 2; ++kk)
    qa[kk] = *(const bf16x8*)(qp + ((size_t)bh * S_ + q0 + rl) * HDIM +
                              kk * 32 + kg * 8);

  f32x4 o_acc[4];
  f32x4 o_l = f32x4{0.f, 0.f, 0.f, 0.f};
#pragma unroll
  for (int nb = 0; nb < 4; ++nb) o_acc[nb] = f32x4{0.f, 0.f, 0.f, 0.f};

  unsigned char* pb = ldsP[w];

  // stage KV tile kt into slot: 512 K units + 512 V units, 2 insts/thread
  auto STAGE = [&](int kt, int slot) {
#pragma unroll
    for (int s = 0; s < 2; ++s) {
      const int Lb = w * 64;                  // wave-uniform, 8 waves x 64
      const int L = Lb + lane;
      const int row = L >> 3;
      const int gu = (L & 7) ^ (row & 7);
      if (s == 0) {
        GLOAD_LDS16(kp + ((size_t)bh * S_ + (size_t)kt * 64 + row) * HDIM + gu * 8,
                    &ldsK[slot][L * 16]);
      } else {
        GLOAD_LDS16(vtp + ((size_t)bh * HDIM + row) * S_ + (size_t)kt * 64 + gu * 8,
                    &ldsV[slot][L * 16]);
      }
    }
  };

  // per-tile pieces (static indexing; called twice per iteration)
  auto QK = [&](int slot, f32x4 sa[4]) {
#pragma unroll
    for (int nb = 0; nb < 4; ++nb) {
      const int row = nb * 16 + rl;
#pragma unroll
      for (int kk = 0; kk < 2; ++kk) {
        bf16x8 kf = *(const bf16x8*)(ldsK[slot] + row * 128 +
                                     ((kk * 64 + kg * 16) ^ ((row & 7) << 4)));
        sa[nb] = __builtin_amdgcn_mfma_f32_16x16x32_bf16(kf, qa[kk], sa[nb], 0, 0, 0);
      }
    }
  };
  auto SMW = [&](const f32x4 sa[4]) {          // exp2 -> bf16 -> P writes
#pragma unroll
    for (int nb = 0; nb < 4; ++nb) {
      bf16x4 pk4;
#pragma unroll
      for (int r = 0; r < 4; ++r)
        pk4[r] = (__bf16)__builtin_amdgcn_exp2f(sa[nb][r]);
      *(bf16x4*)(pb + rl * 128 + ((nb * 32 + kg * 8) ^ pswz)) = pk4;
    }
  };
  auto PVL = [&](int slot) {                   // P read, l, PV
    bf16x8 pa[2];
#pragma unroll
    for (int kk = 0; kk < 2; ++kk)
      pa[kk] = *(const bf16x8*)(pb + rl * 128 + ((kk * 64 + kg * 16) ^ pswz));
    o_l = __builtin_amdgcn_mfma_f32_16x16x32_bf16(pa[0], ones, o_l, 0, 0, 0);
    o_l = __builtin_amdgcn_mfma_f32_16x16x32_bf16(pa[1], ones, o_l, 0, 0, 0);
#pragma unroll
    for (int nb = 0; nb < 4; ++nb) {
      const int row = nb * 16 + rl;
#pragma unroll
      for (int kk = 0; kk < 2; ++kk) {
        bf16x8 vb = *(const bf16x8*)(ldsV[slot] + row * 128 +
                                     ((kk * 64 + kg * 16) ^ ((row & 7) << 4)));
        o_acc[nb] = __builtin_amdgcn_mfma_f32_16x16x32_bf16(pa[kk], vb, o_acc[nb], 0, 0, 0);
      }
    }
  };

  STAGE(0, 0); STAGE(1, 1); STAGE(2, 2); STAGE(3, 3);
  asm volatile("s_waitcnt vmcnt(4) lgkmcnt(0)" ::: "memory"); // tiles 0,1 landed
  __builtin_amdgcn_s_barrier();

  for (int kt = 0; kt < 32; kt += 2) {
    const int s0 = kt & 3, s1 = (kt + 1) & 3;

    f32x4 saA[4], saB[4];
#pragma unroll
    for (int nb = 0; nb < 4; ++nb) { saA[nb] = f32x4{0.f,0.f,0.f,0.f}; saB[nb] = f32x4{0.f,0.f,0.f,0.f}; }

    __builtin_amdgcn_s_setprio(1);
    QK(s0, saA);
    QK(s1, saB);
    __builtin_amdgcn_s_setprio(0);

    SMW(saA);
    asm volatile("s_waitcnt lgkmcnt(0)" ::: "memory");
    __builtin_amdgcn_sched_barrier(0);

    // region: PV_A MFMAs interleave with SM_B VALU (independent, same wave)
    __builtin_amdgcn_s_setprio(1);
    PVL(s0);
    __builtin_amdgcn_s_setprio(0);
    SMW(saB);
    asm volatile("s_waitcnt lgkmcnt(0)" ::: "memory");
    __builtin_amdgcn_sched_barrier(0);

    __builtin_amdgcn_s_setprio(1);
    PVL(s1);
    __builtin_amdgcn_s_setprio(0);

    // publish: all waves done reading slots s0,s1; restage them 2 ahead
    __builtin_amdgcn_s_barrier();
    if (kt + 4 < 32) {
      STAGE(kt + 4, s0); STAGE(kt + 5, s1);
      asm volatile("s_waitcnt vmcnt(4) lgkmcnt(0)" ::: "memory"); // kt+2,kt+3 landed
    } else {
      asm volatile("s_waitcnt vmcnt(0) lgkmcnt(0)" ::: "memory");
    }
    __builtin_amdgcn_s_barrier();
  }

  // epilogue: O[q=kg*4+r][d=nb*16+rl] / l[q]; o_l aligned with o_acc
  const int b = bh >> 4, h = bh & 15;
#pragma unroll
  for (int r = 0; r < 4; ++r) {
    float linv = 1.0f / o_l[r];
    const int row = q0 + kg * 4 + r;
#pragma unroll
    for (int nb = 0; nb < 4; ++nb) {
      float v = o_acc[nb][r] * linv;
      ao[((size_t)b * S_ + row) * EMBED + h * HDIM + nb * 16 + rl] = f2bf(v);
    }
  }
}

// ---------------------------------------------------------------------------
extern "C" void kernel_launch(void* const* d_in, const int* in_sizes, int n_in,
                              void* d_out, int out_size, void* d_ws, size_t ws_size,
                              hipStream_t stream) {
  const float* x    = (const float*)d_in[0];
  const int*   mask = (const int*)d_in[1];
  const float* Wq   = (const float*)d_in[2];
  const float* bq   = (const float*)d_in[3];
  const float* Wk   = (const float*)d_in[4];
  const float* bk   = (const float*)d_in[5];
  const float* Wv   = (const float*)d_in[6];
  const float* bv   = (const float*)d_in[7];
  const float* Wo   = (const float*)d_in[8];
  const float* bo   = (const float*)d_in[9];

  char* ws = (char*)d_ws;
  ushort_t* xb  = (ushort_t*)(ws);
  ushort_t* wqb = (ushort_t*)(ws + 8388608);
  ushort_t* wkb = (ushort_t*)(ws + 10485760);
  ushort_t* wvb = (ushort_t*)(ws + 12582912);
  ushort_t* wob = (ushort_t*)(ws + 14680064);
  ushort_t* qb  = (ushort_t*)(ws + 16777216);
  ushort_t* kb  = (ushort_t*)(ws + 25165824);
  ushort_t* vtb = (ushort_t*)(ws + 33554432);
  ushort_t* aob = (ushort_t*)(ws + 41943040);

  hipLaunchKernelGGL(convert_kernel, dim3(8192), dim3(256), 0, stream,
                     x, Wq, Wk, Wv, Wo, xb, wqb, wkb, wvb, wob);
  hipLaunchKernelGGL(qkv_kernel, dim3(768), dim3(256), 0, stream,
                     xb, wqb, wkb, wvb, bq, bk, bv, mask, qb, kb, vtb);
  hipLaunchKernelGGL(attn_kernel, dim3(512), dim3(512), 0, stream,
                     qb, kb, vtb, aob);
  hipLaunchKernelGGL(gemm_o_kernel, dim3(32, 8), dim3(256), 0, stream,
                     aob, wob, bo, (float*)d_out);
}

// Round 28
// 111.269 us; speedup vs baseline: 1.0461x; 1.0011x over previous
//
#include <hip/hip_runtime.h>

#define DEV __device__ __forceinline__

typedef __bf16 bf16x8 __attribute__((ext_vector_type(8)));
typedef __bf16 bf16x4 __attribute__((ext_vector_type(4)));
typedef float f32x4 __attribute__((ext_vector_type(4)));
typedef unsigned u32x4 __attribute__((ext_vector_type(4)));
typedef unsigned long long u64x2 __attribute__((ext_vector_type(2)));
typedef unsigned short ushort_t;

static constexpr int EMBED = 1024;
static constexpr int NHEAD = 16;
static constexpr int HDIM  = 64;
static constexpr int S_    = 2048;
static constexpr float SCALE_L2E = 0.125f * 1.44269504088896340736f; // (1/sqrt(64))*log2(e)

DEV ushort_t f2bf(float f) {
  unsigned u = __builtin_bit_cast(unsigned, f);
  unsigned r = (u + 0x7fffu + ((u >> 16) & 1u)) >> 16;
  return (ushort_t)r;
}

// async global->LDS, 16B per lane; LDS dest is wave-uniform base + lane*16
#define GLOAD_LDS16(g, l)                                                   \
  __builtin_amdgcn_global_load_lds(                                         \
      (const __attribute__((address_space(1))) unsigned int*)(g),           \
      (__attribute__((address_space(3))) unsigned int*)(l), 16, 0, 0)

// explicit drain of global_load_lds before a publish barrier
#define DRAIN_VM() asm volatile("s_waitcnt vmcnt(0)" ::: "memory")

// ---------------------------------------------------------------------------
// fp32 -> bf16 conversion of x and the four weight matrices
// ---------------------------------------------------------------------------
__global__ __launch_bounds__(256) void convert_kernel(
    const float* __restrict__ x,
    const float* __restrict__ wq, const float* __restrict__ wk,
    const float* __restrict__ wv, const float* __restrict__ wo,
    ushort_t* __restrict__ xb, ushort_t* __restrict__ wqb,
    ushort_t* __restrict__ wkb, ushort_t* __restrict__ wvb,
    ushort_t* __restrict__ wob) {
  size_t i = ((size_t)blockIdx.x * blockDim.x + threadIdx.x) * 4;
  const float* src; ushort_t* dst; size_t off;
  if (i < 4194304u)      { src = x;  dst = xb;  off = i; }
  else if (i < 5242880u) { src = wq; dst = wqb; off = i - 4194304u; }
  else if (i < 6291456u) { src = wk; dst = wkb; off = i - 5242880u; }
  else if (i < 7340032u) { src = wv; dst = wvb; off = i - 6291456u; }
  else                   { src = wo; dst = wob; off = i - 7340032u; }
  float4 v = *(const float4*)(src + off);
  ushort4 o;
  o.x = f2bf(v.x); o.y = f2bf(v.y); o.z = f2bf(v.z); o.w = f2bf(v.w);
  *(ushort4*)(dst + off) = o;
}

// ---------------------------------------------------------------------------
// Merged QKV GEMM, 1-D grid of 768 blocks (R12-green single-buffer m97):
//   bid <256 : Q = xb @ Wq^T  -> [B,H,S,D], (acc+bias)*mask*SCALE_L2E
//   bid <512 : K = xb @ Wk^T  -> [B,H,S,D], (acc+bias)*mask
//   else     : V^T (A=Wv, B=xb) -> [B,H,D,S], acc+bias
// ---------------------------------------------------------------------------
__global__ __launch_bounds__(256) void qkv_kernel(
    const ushort_t* __restrict__ xb, const ushort_t* __restrict__ wqb,
    const ushort_t* __restrict__ wkb, const ushort_t* __restrict__ wvb,
    const float* __restrict__ bq, const float* __restrict__ bk,
    const float* __restrict__ bv, const int* __restrict__ mask,
    ushort_t* __restrict__ qo, ushort_t* __restrict__ ko,
    ushort_t* __restrict__ vto) {
  __shared__ __align__(16) unsigned char ldsA[16384];
  __shared__ __align__(16) unsigned char ldsB[16384];
  __shared__ float maskf[2][128];

  const int bid  = blockIdx.x;
  const int tid  = threadIdx.x;
  const int lane = tid & 63;
  const int w    = tid >> 6;
  const int wm   = (w >> 1) * 64;
  const int wn   = (w & 1) * 64;
  const int rl   = lane & 15;
  const int kg   = lane >> 4;

  int mode, ar0, br0;
  const ushort_t *A, *Bm;
  const float* bias;
  if (bid < 512) {
    mode = bid >> 8;                 // 0=Q, 1=K
    int t = bid & 255;
    ar0 = (t & 31) * 128;            // x rows
    br0 = (t >> 5) * 128;            // weight rows
    A = xb; Bm = mode ? wkb : wqb; bias = mode ? bk : bq;
  } else {
    mode = 2;
    int t = bid - 512;
    ar0 = (t & 7) * 128;             // weight rows
    br0 = (t >> 3) * 128;            // x rows
    A = wvb; Bm = xb; bias = bv;
  }

  if (mode < 2) {
    int hl = tid >> 7, sl = tid & 127;
    int m = ar0 + sl;
    int b = m >> 11, s = m & 2047;
    int h = (br0 >> 6) + hl;
    maskf[hl][sl] = (float)mask[((size_t)b * NHEAD + h) * S_ + s];
  }

  f32x4 acc[4][4];
#pragma unroll
  for (int i = 0; i < 4; ++i)
#pragma unroll
    for (int j = 0; j < 4; ++j) acc[i][j] = f32x4{0.f, 0.f, 0.f, 0.f};

  auto STAGE = [&](int kt) {
    const int k0 = kt * 64;
#pragma unroll
    for (int s = 0; s < 8; ++s) {
      const int basev = s * 256 + w * 64;   // wave-uniform
      const int Lb = basev & 1023;
      const int L = Lb + lane;
      const int row = L >> 3;
      const int gu = (L & 7) ^ (row & 7);
      if (s < 4) {
        GLOAD_LDS16(A + (size_t)(ar0 + row) * EMBED + k0 + gu * 8, &ldsA[Lb * 16]);
      } else {
        GLOAD_LDS16(Bm + (size_t)(br0 + row) * EMBED + k0 + gu * 8, &ldsB[Lb * 16]);
      }
    }
  };

  for (int kt = 0; kt < 16; ++kt) {
    if (kt) __syncthreads();          // all waves done reading previous tile
    STAGE(kt);
    DRAIN_VM();                       // my loads landed
    __syncthreads();                  // everyone's loads landed
#pragma unroll
    for (int kk = 0; kk < 2; ++kk) {
      bf16x8 af[4], bfr[4];
#pragma unroll
      for (int mb = 0; mb < 4; ++mb) {
        const int row = wm + mb * 16 + rl;
        const int off = (kk * 64 + kg * 16) ^ ((row & 7) << 4);
        af[mb] = *(const bf16x8*)(ldsA + row * 128 + off);
      }
#pragma unroll
      for (int nb = 0; nb < 4; ++nb) {
        const int row = wn + nb * 16 + rl;
        const int off = (kk * 64 + kg * 16) ^ ((row & 7) << 4);
        bfr[nb] = *(const bf16x8*)(ldsB + row * 128 + off);
      }
#pragma unroll
      for (int mb = 0; mb < 4; ++mb)
#pragma unroll
        for (int nb = 0; nb < 4; ++nb)
          acc[mb][nb] = __builtin_amdgcn_mfma_f32_16x16x32_bf16(
              af[mb], bfr[nb], acc[mb][nb], 0, 0, 0);
    }
  }

  // epilogue — D layout: row(A idx)=(lane>>4)*4+r, col(B idx)=lane&15
#pragma unroll
  for (int mb = 0; mb < 4; ++mb)
#pragma unroll
    for (int nb = 0; nb < 4; ++nb)
#pragma unroll
      for (int r = 0; r < 4; ++r) {
        int row_l = wm + mb * 16 + kg * 4 + r;
        int col_l = wn + nb * 16 + rl;
        float v = acc[mb][nb][r];
        if (mode < 2) {
          int m = ar0 + row_l, n = br0 + col_l;
          v = (v + bias[n]) * maskf[col_l >> 6][row_l];
          if (mode == 0) v *= SCALE_L2E;
          int b = m >> 11, s = m & 2047, h = n >> 6, d = n & 63;
          ushort_t* o = mode ? ko : qo;
          o[(((size_t)(b * NHEAD + h)) * S_ + s) * HDIM + d] = f2bf(v);
        } else {
          int n = ar0 + row_l, m = br0 + col_l;
          v += bias[n];
          int b = m >> 11, s = m & 2047, h = n >> 6, d = n & 63;
          vto[(((size_t)(b * NHEAD + h)) * HDIM + d) * S_ + s] = f2bf(v);
        }
      }
}

// ---------------------------------------------------------------------------
// O projection GEMM: out[m][n] = aob[m][:] . Wo[n][:] + bo[n]  (fp32 out)
// R12-green single-buffer m97 structure.
// ---------------------------------------------------------------------------
__global__ __launch_bounds__(256) void gemm_o_kernel(
    const ushort_t* __restrict__ A, const ushort_t* __restrict__ Bm,
    const float* __restrict__ bias, float* __restrict__ outp) {
  __shared__ __align__(16) unsigned char ldsA[16384];
  __shared__ __align__(16) unsigned char ldsB[16384];

  const int tid  = threadIdx.x;
  const int lane = tid & 63;
  const int w    = tid >> 6;
  const int ar0  = blockIdx.x * 128;
  const int br0  = blockIdx.y * 128;
  const int wm   = (w >> 1) * 64;
  const int wn   = (w & 1) * 64;
  const int rl   = lane & 15;
  const int kg   = lane >> 4;

  f32x4 acc[4][4];
#pragma unroll
  for (int i = 0; i < 4; ++i)
#pragma unroll
    for (int j = 0; j < 4; ++j) acc[i][j] = f32x4{0.f, 0.f, 0.f, 0.f};

  auto STAGE = [&](int kt) {
    const int k0 = kt * 64;
#pragma unroll
    for (int s = 0; s < 8; ++s) {
      const int basev = s * 256 + w * 64;
      const int Lb = basev & 1023;
      const int L = Lb + lane;
      const int row = L >> 3;
      const int gu = (L & 7) ^ (row & 7);
      if (s < 4) {
        GLOAD_LDS16(A + (size_t)(ar0 + row) * EMBED + k0 + gu * 8, &ldsA[Lb * 16]);
      } else {
        GLOAD_LDS16(Bm + (size_t)(br0 + row) * EMBED + k0 + gu * 8, &ldsB[Lb * 16]);
      }
    }
  };

  for (int kt = 0; kt < 16; ++kt) {
    if (kt) __syncthreads();
    STAGE(kt);
    DRAIN_VM();
    __syncthreads();
#pragma unroll
    for (int kk = 0; kk < 2; ++kk) {
      bf16x8 af[4], bfr[4];
#pragma unroll
      for (int mb = 0; mb < 4; ++mb) {
        const int row = wm + mb * 16 + rl;
        const int off = (kk * 64 + kg * 16) ^ ((row & 7) << 4);
        af[mb] = *(const bf16x8*)(ldsA + row * 128 + off);
      }
#pragma unroll
      for (int nb = 0; nb < 4; ++nb) {
        const int row = wn + nb * 16 + rl;
        const int off = (kk * 64 + kg * 16) ^ ((row & 7) << 4);
        bfr[nb] = *(const bf16x8*)(ldsB + row * 128 + off);
      }
#pragma unroll
      for (int mb = 0; mb < 4; ++mb)
#pragma unroll
        for (int nb = 0; nb < 4; ++nb)
          acc[mb][nb] = __builtin_amdgcn_mfma_f32_16x16x32_bf16(
              af[mb], bfr[nb], acc[mb][nb], 0, 0, 0);
    }
  }

#pragma unroll
  for (int mb = 0; mb < 4; ++mb)
#pragma unroll
    for (int nb = 0; nb < 4; ++nb)
#pragma unroll
      for (int r = 0; r < 4; ++r) {
        int m = ar0 + wm + mb * 16 + kg * 4 + r;
        int n = br0 + wn + nb * 16 + rl;
        outp[(size_t)m * EMBED + n] = acc[mb][nb][r] + bias[n];
      }
}

// ---------------------------------------------------------------------------
// Flash attention, swapped-QK^T, fixed-exponent softmax — 2-TILE UNROLL
// (R25-green structure) with CONFLICT-FREE P SWIZZLE:
//   write byte = (2*key) ^ ((rl&7)<<4) ^ (rl&8)  -> slot bijective over the
//   16 slots within each 16-lane issue group (was 4-way write conflict);
//   read compensates: halves of each 16B fragment live at B+(rl&8) and
//   B+8-(rl&8) (XOR-by-8 swaps halves within the aligned 16B window),
//   assembled from two u64 loads -> banks 4*(r7^c)+2*rl8: all 32 banks
//   exactly once per 16-lane group. Values bit-identical.
// LDS: K 4x8KB + V 4x8KB + P 8x2KB = 80KB -> 2 blocks/CU.
// ---------------------------------------------------------------------------
__global__ __launch_bounds__(512) void attn_kernel(
    const ushort_t* __restrict__ qp, const ushort_t* __restrict__ kp,
    const ushort_t* __restrict__ vtp, ushort_t* __restrict__ ao) {
  __shared__ __align__(16) unsigned char ldsK[4][8192];
  __shared__ __align__(16) unsigned char ldsV[4][8192];
  __shared__ __align__(16) unsigned char ldsP[8][2048];

  const int bid  = blockIdx.x;
  const int bh   = (bid & 7) * 4 + (bid >> 7); // XCD-resident head slice
  const int qt   = (bid >> 3) & 15;
  const int tid  = threadIdx.x;
  const int lane = tid & 63;
  const int w    = tid >> 6;                  // 0..7
  const int q0   = qt * 128 + w * 16;         // wave's q base (16 rows)
  const int rl   = lane & 15;
  const int kg   = lane >> 4;
  const int pswz = (rl & 7) << 4;
  const int rl8  = rl & 8;                    // P half-swap bit

  const bf16x8 ones = __builtin_bit_cast(bf16x8,
      u32x4{0x3F803F80u, 0x3F803F80u, 0x3F803F80u, 0x3F803F80u});

  // Q fragments (B-operand): lane (rl,kg) holds Q[q=rl][d=kk*32+kg*8..+8]
  bf16x8 qa[2];
#pragma unroll
  for (int kk = 0; kk < 2; ++kk)
    qa[kk] = *(const bf16x8*)(qp + ((size_t)bh * S_ + q0 + rl) * HDIM +
                              kk * 32 + kg * 8);

  f32x4 o_acc[4];
  f32x4 o_l = f32x4{0.f, 0.f, 0.f, 0.f};
#pragma unroll
  for (int nb = 0; nb < 4; ++nb) o_acc[nb] = f32x4{0.f, 0.f, 0.f, 0.f};

  unsigned char* pb = ldsP[w];

  // stage KV tile kt into slot: 512 K units + 512 V units, 2 insts/thread
  auto STAGE = [&](int kt, int slot) {
#pragma unroll
    for (int s = 0; s < 2; ++s) {
      const int Lb = w * 64;                  // wave-uniform, 8 waves x 64
      const int L = Lb + lane;
      const int row = L >> 3;
      const int gu = (L & 7) ^ (row & 7);
      if (s == 0) {
        GLOAD_LDS16(kp + ((size_t)bh * S_ + (size_t)kt * 64 + row) * HDIM + gu * 8,
                    &ldsK[slot][L * 16]);
      } else {
        GLOAD_LDS16(vtp + ((size_t)bh * HDIM + row) * S_ + (size_t)kt * 64 + gu * 8,
                    &ldsV[slot][L * 16]);
      }
    }
  };

  // per-tile pieces (static indexing; called twice per iteration)
  auto QK = [&](int slot, f32x4 sa[4]) {
#pragma unroll
    for (int nb = 0; nb < 4; ++nb) {
      const int row = nb * 16 + rl;
#pragma unroll
      for (int kk = 0; kk < 2; ++kk) {
        bf16x8 kf = *(const bf16x8*)(ldsK[slot] + row * 128 +
                                     ((kk * 64 + kg * 16) ^ ((row & 7) << 4)));
        sa[nb] = __builtin_amdgcn_mfma_f32_16x16x32_bf16(kf, qa[kk], sa[nb], 0, 0, 0);
      }
    }
  };
  auto SMW = [&](const f32x4 sa[4]) {          // exp2 -> bf16 -> P writes
#pragma unroll
    for (int nb = 0; nb < 4; ++nb) {
      bf16x4 pk4;
#pragma unroll
      for (int r = 0; r < 4; ++r)
        pk4[r] = (__bf16)__builtin_amdgcn_exp2f(sa[nb][r]);
      *(bf16x4*)(pb + rl * 128 + ((nb * 32 + kg * 8) ^ pswz ^ rl8)) = pk4;
    }
  };
  auto PVL = [&](int slot) {                   // P read, l, PV
    bf16x8 pa[2];
#pragma unroll
    for (int kk = 0; kk < 2; ++kk) {
      const unsigned char* base = pb + rl * 128 + ((kk * 64 + kg * 16) ^ pswz);
      unsigned long long lo = *(const unsigned long long*)(base + rl8);
      unsigned long long hi = *(const unsigned long long*)(base + 8 - rl8);
      pa[kk] = __builtin_bit_cast(bf16x8, u64x2{lo, hi});
    }
    o_l = __builtin_amdgcn_mfma_f32_16x16x32_bf16(pa[0], ones, o_l, 0, 0, 0);
    o_l = __builtin_amdgcn_mfma_f32_16x16x32_bf16(pa[1], ones, o_l, 0, 0, 0);
#pragma unroll
    for (int nb = 0; nb < 4; ++nb) {
      const int row = nb * 16 + rl;
#pragma unroll
      for (int kk = 0; kk < 2; ++kk) {
        bf16x8 vb = *(const bf16x8*)(ldsV[slot] + row * 128 +
                                     ((kk * 64 + kg * 16) ^ ((row & 7) << 4)));
        o_acc[nb] = __builtin_amdgcn_mfma_f32_16x16x32_bf16(pa[kk], vb, o_acc[nb], 0, 0, 0);
      }
    }
  };

  STAGE(0, 0); STAGE(1, 1); STAGE(2, 2); STAGE(3, 3);
  asm volatile("s_waitcnt vmcnt(4) lgkmcnt(0)" ::: "memory"); // tiles 0,1 landed
  __builtin_amdgcn_s_barrier();

  for (int kt = 0; kt < 32; kt += 2) {
    const int s0 = kt & 3, s1 = (kt + 1) & 3;

    f32x4 saA[4], saB[4];
#pragma unroll
    for (int nb = 0; nb < 4; ++nb) { saA[nb] = f32x4{0.f,0.f,0.f,0.f}; saB[nb] = f32x4{0.f,0.f,0.f,0.f}; }

    __builtin_amdgcn_s_setprio(1);
    QK(s0, saA);
    QK(s1, saB);
    __builtin_amdgcn_s_setprio(0);

    SMW(saA);
    asm volatile("s_waitcnt lgkmcnt(0)" ::: "memory");
    __builtin_amdgcn_sched_barrier(0);

    // region: PV_A MFMAs interleave with SM_B VALU (independent, same wave)
    __builtin_amdgcn_s_setprio(1);
    PVL(s0);
    __builtin_amdgcn_s_setprio(0);
    SMW(saB);
    asm volatile("s_waitcnt lgkmcnt(0)" ::: "memory");
    __builtin_amdgcn_sched_barrier(0);

    __builtin_amdgcn_s_setprio(1);
    PVL(s1);
    __builtin_amdgcn_s_setprio(0);

    // publish: all waves done reading slots s0,s1; restage them 2 ahead
    __builtin_amdgcn_s_barrier();
    if (kt + 4 < 32) {
      STAGE(kt + 4, s0); STAGE(kt + 5, s1);
      asm volatile("s_waitcnt vmcnt(4) lgkmcnt(0)" ::: "memory"); // kt+2,kt+3 landed
    } else {
      asm volatile("s_waitcnt vmcnt(0) lgkmcnt(0)" ::: "memory");
    }
    __builtin_amdgcn_s_barrier();
  }

  // epilogue: O[q=kg*4+r][d=nb*16+rl] / l[q]; o_l aligned with o_acc
  const int b = bh >> 4, h = bh & 15;
#pragma unroll
  for (int r = 0; r < 4; ++r) {
    float linv = 1.0f / o_l[r];
    const int row = q0 + kg * 4 + r;
#pragma unroll
    for (int nb = 0; nb < 4; ++nb) {
      float v = o_acc[nb][r] * linv;
      ao[((size_t)b * S_ + row) * EMBED + h * HDIM + nb * 16 + rl] = f2bf(v);
    }
  }
}

// ---------------------------------------------------------------------------
extern "C" void kernel_launch(void* const* d_in, const int* in_sizes, int n_in,
                              void* d_out, int out_size, void* d_ws, size_t ws_size,
                              hipStream_t stream) {
  const float* x    = (const float*)d_in[0];
  const int*   mask = (const int*)d_in[1];
  const float* Wq   = (const float*)d_in[2];
  const float* bq   = (const float*)d_in[3];
  const float* Wk   = (const float*)d_in[4];
  const float* bk   = (const float*)d_in[5];
  const float* Wv   = (const float*)d_in[6];
  const float* bv   = (const float*)d_in[7];
  const float* Wo   = (const float*)d_in[8];
  const float* bo   = (const float*)d_in[9];

  char* ws = (char*)d_ws;
  ushort_t* xb  = (ushort_t*)(ws);
  ushort_t* wqb = (ushort_t*)(ws + 8388608);
  ushort_t* wkb = (ushort_t*)(ws + 10485760);
  ushort_t* wvb = (ushort_t*)(ws + 12582912);
  ushort_t* wob = (ushort_t*)(ws + 14680064);
  ushort_t* qb  = (ushort_t*)(ws + 16777216);
  ushort_t* kb  = (ushort_t*)(ws + 25165824);
  ushort_t* vtb = (ushort_t*)(ws + 33554432);
  ushort_t* aob = (ushort_t*)(ws + 41943040);

  hipLaunchKernelGGL(convert_kernel, dim3(8192), dim3(256), 0, stream,
                     x, Wq, Wk, Wv, Wo, xb, wqb, wkb, wvb, wob);
  hipLaunchKernelGGL(qkv_kernel, dim3(768), dim3(256), 0, stream,
                     xb, wqb, wkb, wvb, bq, bk, bv, mask, qb, kb, vtb);
  hipLaunchKernelGGL(attn_kernel, dim3(512), dim3(512), 0, stream,
                     qb, kb, vtb, aob);
  hipLaunchKernelGGL(gemm_o_kernel, dim3(32, 8), dim3(256), 0, stream,
                     aob, wob, bo, (float*)d_out);
}

// Round 29
// 108.800 us; speedup vs baseline: 1.0699x; 1.0227x over previous
//
#include <hip/hip_runtime.h>

#define DEV __device__ __forceinline__

typedef __bf16 bf16x8 __attribute__((ext_vector_type(8)));
typedef __bf16 bf16x4 __attribute__((ext_vector_type(4)));
typedef float f32x4 __attribute__((ext_vector_type(4)));
typedef unsigned u32x4 __attribute__((ext_vector_type(4)));
typedef unsigned long long u64x2 __attribute__((ext_vector_type(2)));
typedef unsigned short ushort_t;

static constexpr int EMBED = 1024;
static constexpr int NHEAD = 16;
static constexpr int HDIM  = 64;
static constexpr int S_    = 2048;
static constexpr float SCALE_L2E = 0.125f * 1.44269504088896340736f; // (1/sqrt(64))*log2(e)

DEV ushort_t f2bf(float f) {
  unsigned u = __builtin_bit_cast(unsigned, f);
  unsigned r = (u + 0x7fffu + ((u >> 16) & 1u)) >> 16;
  return (ushort_t)r;
}

// async global->LDS, 16B per lane; LDS dest is wave-uniform base + lane*16
#define GLOAD_LDS16(g, l)                                                   \
  __builtin_amdgcn_global_load_lds(                                         \
      (const __attribute__((address_space(1))) unsigned int*)(g),           \
      (__attribute__((address_space(3))) unsigned int*)(l), 16, 0, 0)

// explicit drain of global_load_lds before a publish barrier
#define DRAIN_VM() asm volatile("s_waitcnt vmcnt(0)" ::: "memory")

// ---------------------------------------------------------------------------
// fp32 -> bf16 conversion of x and the four weight matrices
// ---------------------------------------------------------------------------
__global__ __launch_bounds__(256) void convert_kernel(
    const float* __restrict__ x,
    const float* __restrict__ wq, const float* __restrict__ wk,
    const float* __restrict__ wv, const float* __restrict__ wo,
    ushort_t* __restrict__ xb, ushort_t* __restrict__ wqb,
    ushort_t* __restrict__ wkb, ushort_t* __restrict__ wvb,
    ushort_t* __restrict__ wob) {
  size_t i = ((size_t)blockIdx.x * blockDim.x + threadIdx.x) * 4;
  const float* src; ushort_t* dst; size_t off;
  if (i < 4194304u)      { src = x;  dst = xb;  off = i; }
  else if (i < 5242880u) { src = wq; dst = wqb; off = i - 4194304u; }
  else if (i < 6291456u) { src = wk; dst = wkb; off = i - 5242880u; }
  else if (i < 7340032u) { src = wv; dst = wvb; off = i - 6291456u; }
  else                   { src = wo; dst = wob; off = i - 7340032u; }
  float4 v = *(const float4*)(src + off);
  ushort4 o;
  o.x = f2bf(v.x); o.y = f2bf(v.y); o.z = f2bf(v.z); o.w = f2bf(v.w);
  *(ushort4*)(dst + off) = o;
}

// ---------------------------------------------------------------------------
// Merged QKV GEMM, 1-D grid of 768 blocks (R12-green single-buffer m97):
//   bid <256 : Q = xb @ Wq^T  -> [B,H,S,D], (acc+bias)*mask*SCALE_L2E
//   bid <512 : K = xb @ Wk^T  -> [B,H,S,D], (acc+bias)*mask
//   else     : V^T (A=Wv, B=xb) -> [B,H,D,S], acc+bias
// ---------------------------------------------------------------------------
__global__ __launch_bounds__(256) void qkv_kernel(
    const ushort_t* __restrict__ xb, const ushort_t* __restrict__ wqb,
    const ushort_t* __restrict__ wkb, const ushort_t* __restrict__ wvb,
    const float* __restrict__ bq, const float* __restrict__ bk,
    const float* __restrict__ bv, const int* __restrict__ mask,
    ushort_t* __restrict__ qo, ushort_t* __restrict__ ko,
    ushort_t* __restrict__ vto) {
  __shared__ __align__(16) unsigned char ldsA[16384];
  __shared__ __align__(16) unsigned char ldsB[16384];
  __shared__ float maskf[2][128];

  const int bid  = blockIdx.x;
  const int tid  = threadIdx.x;
  const int lane = tid & 63;
  const int w    = tid >> 6;
  const int wm   = (w >> 1) * 64;
  const int wn   = (w & 1) * 64;
  const int rl   = lane & 15;
  const int kg   = lane >> 4;

  int mode, ar0, br0;
  const ushort_t *A, *Bm;
  const float* bias;
  if (bid < 512) {
    mode = bid >> 8;                 // 0=Q, 1=K
    int t = bid & 255;
    ar0 = (t & 31) * 128;            // x rows
    br0 = (t >> 5) * 128;            // weight rows
    A = xb; Bm = mode ? wkb : wqb; bias = mode ? bk : bq;
  } else {
    mode = 2;
    int t = bid - 512;
    ar0 = (t & 7) * 128;             // weight rows
    br0 = (t >> 3) * 128;            // x rows
    A = wvb; Bm = xb; bias = bv;
  }

  if (mode < 2) {
    int hl = tid >> 7, sl = tid & 127;
    int m = ar0 + sl;
    int b = m >> 11, s = m & 2047;
    int h = (br0 >> 6) + hl;
    maskf[hl][sl] = (float)mask[((size_t)b * NHEAD + h) * S_ + s];
  }

  f32x4 acc[4][4];
#pragma unroll
  for (int i = 0; i < 4; ++i)
#pragma unroll
    for (int j = 0; j < 4; ++j) acc[i][j] = f32x4{0.f, 0.f, 0.f, 0.f};

  auto STAGE = [&](int kt) {
    const int k0 = kt * 64;
#pragma unroll
    for (int s = 0; s < 8; ++s) {
      const int basev = s * 256 + w * 64;   // wave-uniform
      const int Lb = basev & 1023;
      const int L = Lb + lane;
      const int row = L >> 3;
      const int gu = (L & 7) ^ (row & 7);
      if (s < 4) {
        GLOAD_LDS16(A + (size_t)(ar0 + row) * EMBED + k0 + gu * 8, &ldsA[Lb * 16]);
      } else {
        GLOAD_LDS16(Bm + (size_t)(br0 + row) * EMBED + k0 + gu * 8, &ldsB[Lb * 16]);
      }
    }
  };

  for (int kt = 0; kt < 16; ++kt) {
    if (kt) __syncthreads();          // all waves done reading previous tile
    STAGE(kt);
    DRAIN_VM();                       // my loads landed
    __syncthreads();                  // everyone's loads landed
#pragma unroll
    for (int kk = 0; kk < 2; ++kk) {
      bf16x8 af[4], bfr[4];
#pragma unroll
      for (int mb = 0; mb < 4; ++mb) {
        const int row = wm + mb * 16 + rl;
        const int off = (kk * 64 + kg * 16) ^ ((row & 7) << 4);
        af[mb] = *(const bf16x8*)(ldsA + row * 128 + off);
      }
#pragma unroll
      for (int nb = 0; nb < 4; ++nb) {
        const int row = wn + nb * 16 + rl;
        const int off = (kk * 64 + kg * 16) ^ ((row & 7) << 4);
        bfr[nb] = *(const bf16x8*)(ldsB + row * 128 + off);
      }
#pragma unroll
      for (int mb = 0; mb < 4; ++mb)
#pragma unroll
        for (int nb = 0; nb < 4; ++nb)
          acc[mb][nb] = __builtin_amdgcn_mfma_f32_16x16x32_bf16(
              af[mb], bfr[nb], acc[mb][nb], 0, 0, 0);
    }
  }

  // epilogue — D layout: row(A idx)=(lane>>4)*4+r, col(B idx)=lane&15
#pragma unroll
  for (int mb = 0; mb < 4; ++mb)
#pragma unroll
    for (int nb = 0; nb < 4; ++nb)
#pragma unroll
      for (int r = 0; r < 4; ++r) {
        int row_l = wm + mb * 16 + kg * 4 + r;
        int col_l = wn + nb * 16 + rl;
        float v = acc[mb][nb][r];
        if (mode < 2) {
          int m = ar0 + row_l, n = br0 + col_l;
          v = (v + bias[n]) * maskf[col_l >> 6][row_l];
          if (mode == 0) v *= SCALE_L2E;
          int b = m >> 11, s = m & 2047, h = n >> 6, d = n & 63;
          ushort_t* o = mode ? ko : qo;
          o[(((size_t)(b * NHEAD + h)) * S_ + s) * HDIM + d] = f2bf(v);
        } else {
          int n = ar0 + row_l, m = br0 + col_l;
          v += bias[n];
          int b = m >> 11, s = m & 2047, h = n >> 6, d = n & 63;
          vto[(((size_t)(b * NHEAD + h)) * HDIM + d) * S_ + s] = f2bf(v);
        }
      }
}

// ---------------------------------------------------------------------------
// O projection GEMM: out[m][n] = aob[m][:] . Wo[n][:] + bo[n]  (fp32 out)
// 128x64 tiles -> grid (32,16) = 512 blocks = 2 blocks/CU (was 1/CU at
// 128x128): inter-block overlap hides the per-K-step staging drains
// (m114 mechanism). Waves 2x2 over (128,64); acc 4x2; LDS 24KB.
// Accumulation order per output unchanged -> bitwise-identical numerics.
// ---------------------------------------------------------------------------
__global__ __launch_bounds__(256) void gemm_o_kernel(
    const ushort_t* __restrict__ A, const ushort_t* __restrict__ Bm,
    const float* __restrict__ bias, float* __restrict__ outp) {
  __shared__ __align__(16) unsigned char ldsA[16384];
  __shared__ __align__(16) unsigned char ldsB[8192];

  const int tid  = threadIdx.x;
  const int lane = tid & 63;
  const int w    = tid >> 6;
  const int ar0  = blockIdx.x * 128;
  const int br0  = blockIdx.y * 64;
  const int wm   = (w >> 1) * 64;
  const int wn   = (w & 1) * 32;
  const int rl   = lane & 15;
  const int kg   = lane >> 4;

  f32x4 acc[4][2];
#pragma unroll
  for (int i = 0; i < 4; ++i)
#pragma unroll
    for (int j = 0; j < 2; ++j) acc[i][j] = f32x4{0.f, 0.f, 0.f, 0.f};

  auto STAGE = [&](int kt) {
    const int k0 = kt * 64;
#pragma unroll
    for (int s = 0; s < 6; ++s) {
      if (s < 4) {
        const int Lb = s * 256 + w * 64;      // wave-uniform, 1024 A-units
        const int L = Lb + lane;
        const int row = L >> 3;
        const int gu = (L & 7) ^ (row & 7);
        GLOAD_LDS16(A + (size_t)(ar0 + row) * EMBED + k0 + gu * 8, &ldsA[Lb * 16]);
      } else {
        const int Lb = (s - 4) * 256 + w * 64; // wave-uniform, 512 B-units
        const int L = Lb + lane;
        const int row = L >> 3;
        const int gu = (L & 7) ^ (row & 7);
        GLOAD_LDS16(Bm + (size_t)(br0 + row) * EMBED + k0 + gu * 8, &ldsB[Lb * 16]);
      }
    }
  };

  for (int kt = 0; kt < 16; ++kt) {
    if (kt) __syncthreads();
    STAGE(kt);
    DRAIN_VM();
    __syncthreads();
#pragma unroll
    for (int kk = 0; kk < 2; ++kk) {
      bf16x8 af[4], bfr[2];
#pragma unroll
      for (int mb = 0; mb < 4; ++mb) {
        const int row = wm + mb * 16 + rl;
        const int off = (kk * 64 + kg * 16) ^ ((row & 7) << 4);
        af[mb] = *(const bf16x8*)(ldsA + row * 128 + off);
      }
#pragma unroll
      for (int nb = 0; nb < 2; ++nb) {
        const int row = wn + nb * 16 + rl;
        const int off = (kk * 64 + kg * 16) ^ ((row & 7) << 4);
        bfr[nb] = *(const bf16x8*)(ldsB + row * 128 + off);
      }
#pragma unroll
      for (int mb = 0; mb < 4; ++mb)
#pragma unroll
        for (int nb = 0; nb < 2; ++nb)
          acc[mb][nb] = __builtin_amdgcn_mfma_f32_16x16x32_bf16(
              af[mb], bfr[nb], acc[mb][nb], 0, 0, 0);
    }
  }

#pragma unroll
  for (int mb = 0; mb < 4; ++mb)
#pragma unroll
    for (int nb = 0; nb < 2; ++nb)
#pragma unroll
      for (int r = 0; r < 4; ++r) {
        int m = ar0 + wm + mb * 16 + kg * 4 + r;
        int n = br0 + wn + nb * 16 + rl;
        outp[(size_t)m * EMBED + n] = acc[mb][nb][r] + bias[n];
      }
}

// ---------------------------------------------------------------------------
// Flash attention, swapped-QK^T, fixed-exponent softmax — 2-TILE UNROLL
// (R25-green structure) with CONFLICT-FREE P SWIZZLE (R28-green):
//   write byte = (2*key) ^ ((rl&7)<<4) ^ (rl&8); read compensates via two
//   u64 loads at B+(rl&8) and B+8-(rl&8). SQ_LDS_BANK_CONFLICT = 0.
// LDS: K 4x8KB + V 4x8KB + P 8x2KB = 80KB -> 2 blocks/CU.
// ---------------------------------------------------------------------------
__global__ __launch_bounds__(512) void attn_kernel(
    const ushort_t* __restrict__ qp, const ushort_t* __restrict__ kp,
    const ushort_t* __restrict__ vtp, ushort_t* __restrict__ ao) {
  __shared__ __align__(16) unsigned char ldsK[4][8192];
  __shared__ __align__(16) unsigned char ldsV[4][8192];
  __shared__ __align__(16) unsigned char ldsP[8][2048];

  const int bid  = blockIdx.x;
  const int bh   = (bid & 7) * 4 + (bid >> 7); // XCD-resident head slice
  const int qt   = (bid >> 3) & 15;
  const int tid  = threadIdx.x;
  const int lane = tid & 63;
  const int w    = tid >> 6;                  // 0..7
  const int q0   = qt * 128 + w * 16;         // wave's q base (16 rows)
  const int rl   = lane & 15;
  const int kg   = lane >> 4;
  const int pswz = (rl & 7) << 4;
  const int rl8  = rl & 8;                    // P half-swap bit

  const bf16x8 ones = __builtin_bit_cast(bf16x8,
      u32x4{0x3F803F80u, 0x3F803F80u, 0x3F803F80u, 0x3F803F80u});

  // Q fragments (B-operand): lane (rl,kg) holds Q[q=rl][d=kk*32+kg*8..+8]
  bf16x8 qa[2];
#pragma unroll
  for (int kk = 0; kk < 2; ++kk)
    qa[kk] = *(const bf16x8*)(qp + ((size_t)bh * S_ + q0 + rl) * HDIM +
                              kk * 32 + kg * 8);

  f32x4 o_acc[4];
  f32x4 o_l = f32x4{0.f, 0.f, 0.f, 0.f};
#pragma unroll
  for (int nb = 0; nb < 4; ++nb) o_acc[nb] = f32x4{0.f, 0.f, 0.f, 0.f};

  unsigned char* pb = ldsP[w];

  // stage KV tile kt into slot: 512 K units + 512 V units, 2 insts/thread
  auto STAGE = [&](int kt, int slot) {
#pragma unroll
    for (int s = 0; s < 2; ++s) {
      const int Lb = w * 64;                  // wave-uniform, 8 waves x 64
      const int L = Lb + lane;
      const int row = L >> 3;
      const int gu = (L & 7) ^ (row & 7);
      if (s == 0) {
        GLOAD_LDS16(kp + ((size_t)bh * S_ + (size_t)kt * 64 + row) * HDIM + gu * 8,
                    &ldsK[slot][L * 16]);
      } else {
        GLOAD_LDS16(vtp + ((size_t)bh * HDIM + row) * S_ + (size_t)kt * 64 + gu * 8,
                    &ldsV[slot][L * 16]);
      }
    }
  };

  // per-tile pieces (static indexing; called twice per iteration)
  auto QK = [&](int slot, f32x4 sa[4]) {
#pragma unroll
    for (int nb = 0; nb < 4; ++nb) {
      const int row = nb * 16 + rl;
#pragma unroll
      for (int kk = 0; kk < 2; ++kk) {
        bf16x8 kf = *(const bf16x8*)(ldsK[slot] + row * 128 +
                                     ((kk * 64 + kg * 16) ^ ((row & 7) << 4)));
        sa[nb] = __builtin_amdgcn_mfma_f32_16x16x32_bf16(kf, qa[kk], sa[nb], 0, 0, 0);
      }
    }
  };
  auto SMW = [&](const f32x4 sa[4]) {          // exp2 -> bf16 -> P writes
#pragma unroll
    for (int nb = 0; nb < 4; ++nb) {
      bf16x4 pk4;
#pragma unroll
      for (int r = 0; r < 4; ++r)
        pk4[r] = (__bf16)__builtin_amdgcn_exp2f(sa[nb][r]);
      *(bf16x4*)(pb + rl * 128 + ((nb * 32 + kg * 8) ^ pswz ^ rl8)) = pk4;
    }
  };
  auto PVL = [&](int slot) {                   // P read, l, PV
    bf16x8 pa[2];
#pragma unroll
    for (int kk = 0; kk < 2; ++kk) {
      const unsigned char* base = pb + rl * 128 + ((kk * 64 + kg * 16) ^ pswz);
      unsigned long long lo = *(const unsigned long long*)(base + rl8);
      unsigned long long hi = *(const unsigned long long*)(base + 8 - rl8);
      pa[kk] = __builtin_bit_cast(bf16x8, u64x2{lo, hi});
    }
    o_l = __builtin_amdgcn_mfma_f32_16x16x32_bf16(pa[0], ones, o_l, 0, 0, 0);
    o_l = __builtin_amdgcn_mfma_f32_16x16x32_bf16(pa[1], ones, o_l, 0, 0, 0);
#pragma unroll
    for (int nb = 0; nb < 4; ++nb) {
      const int row = nb * 16 + rl;
#pragma unroll
      for (int kk = 0; kk < 2; ++kk) {
        bf16x8 vb = *(const bf16x8*)(ldsV[slot] + row * 128 +
                                     ((kk * 64 + kg * 16) ^ ((row & 7) << 4)));
        o_acc[nb] = __builtin_amdgcn_mfma_f32_16x16x32_bf16(pa[kk], vb, o_acc[nb], 0, 0, 0);
      }
    }
  };

  STAGE(0, 0); STAGE(1, 1); STAGE(2, 2); STAGE(3, 3);
  asm volatile("s_waitcnt vmcnt(4) lgkmcnt(0)" ::: "memory"); // tiles 0,1 landed
  __builtin_amdgcn_s_barrier();

  for (int kt = 0; kt < 32; kt += 2) {
    const int s0 = kt & 3, s1 = (kt + 1) & 3;

    f32x4 saA[4], saB[4];
#pragma unroll
    for (int nb = 0; nb < 4; ++nb) { saA[nb] = f32x4{0.f,0.f,0.f,0.f}; saB[nb] = f32x4{0.f,0.f,0.f,0.f}; }

    __builtin_amdgcn_s_setprio(1);
    QK(s0, saA);
    QK(s1, saB);
    __builtin_amdgcn_s_setprio(0);

    SMW(saA);
    asm volatile("s_waitcnt lgkmcnt(0)" ::: "memory");
    __builtin_amdgcn_sched_barrier(0);

    // region: PV_A MFMAs interleave with SM_B VALU (independent, same wave)
    __builtin_amdgcn_s_setprio(1);
    PVL(s0);
    __builtin_amdgcn_s_setprio(0);
    SMW(saB);
    asm volatile("s_waitcnt lgkmcnt(0)" ::: "memory");
    __builtin_amdgcn_sched_barrier(0);

    __builtin_amdgcn_s_setprio(1);
    PVL(s1);
    __builtin_amdgcn_s_setprio(0);

    // publish: all waves done reading slots s0,s1; restage them 2 ahead
    __builtin_amdgcn_s_barrier();
    if (kt + 4 < 32) {
      STAGE(kt + 4, s0); STAGE(kt + 5, s1);
      asm volatile("s_waitcnt vmcnt(4) lgkmcnt(0)" ::: "memory"); // kt+2,kt+3 landed
    } else {
      asm volatile("s_waitcnt vmcnt(0) lgkmcnt(0)" ::: "memory");
    }
    __builtin_amdgcn_s_barrier();
  }

  // epilogue: O[q=kg*4+r][d=nb*16+rl] / l[q]; o_l aligned with o_acc
  const int b = bh >> 4, h = bh & 15;
#pragma unroll
  for (int r = 0; r < 4; ++r) {
    float linv = 1.0f / o_l[r];
    const int row = q0 + kg * 4 + r;
#pragma unroll
    for (int nb = 0; nb < 4; ++nb) {
      float v = o_acc[nb][r] * linv;
      ao[((size_t)b * S_ + row) * EMBED + h * HDIM + nb * 16 + rl] = f2bf(v);
    }
  }
}

// ---------------------------------------------------------------------------
extern "C" void kernel_launch(void* const* d_in, const int* in_sizes, int n_in,
                              void* d_out, int out_size, void* d_ws, size_t ws_size,
                              hipStream_t stream) {
  const float* x    = (const float*)d_in[0];
  const int*   mask = (const int*)d_in[1];
  const float* Wq   = (const float*)d_in[2];
  const float* bq   = (const float*)d_in[3];
  const float* Wk   = (const float*)d_in[4];
  const float* bk   = (const float*)d_in[5];
  const float* Wv   = (const float*)d_in[6];
  const float* bv   = (const float*)d_in[7];
  const float* Wo   = (const float*)d_in[8];
  const float* bo   = (const float*)d_in[9];

  char* ws = (char*)d_ws;
  ushort_t* xb  = (ushort_t*)(ws);
  ushort_t* wqb = (ushort_t*)(ws + 8388608);
  ushort_t* wkb = (ushort_t*)(ws + 10485760);
  ushort_t* wvb = (ushort_t*)(ws + 12582912);
  ushort_t* wob = (ushort_t*)(ws + 14680064);
  ushort_t* qb  = (ushort_t*)(ws + 16777216);
  ushort_t* kb  = (ushort_t*)(ws + 25165824);
  ushort_t* vtb = (ushort_t*)(ws + 33554432);
  ushort_t* aob = (ushort_t*)(ws + 41943040);

  hipLaunchKernelGGL(convert_kernel, dim3(8192), dim3(256), 0, stream,
                     x, Wq, Wk, Wv, Wo, xb, wqb, wkb, wvb, wob);
  hipLaunchKernelGGL(qkv_kernel, dim3(768), dim3(256), 0, stream,
                     xb, wqb, wkb, wvb, bq, bk, bv, mask, qb, kb, vtb);
  hipLaunchKernelGGL(attn_kernel, dim3(512), dim3(512), 0, stream,
                     qb, kb, vtb, aob);
  hipLaunchKernelGGL(gemm_o_kernel, dim3(32, 16), dim3(256), 0, stream,
                     aob, wob, bo, (float*)d_out);
}

// Round 30
// 108.587 us; speedup vs baseline: 1.0720x; 1.0020x over previous
//
#include <hip/hip_runtime.h>

#define DEV __device__ __forceinline__

typedef __bf16 bf16x8 __attribute__((ext_vector_type(8)));
typedef __bf16 bf16x4 __attribute__((ext_vector_type(4)));
typedef float f32x4 __attribute__((ext_vector_type(4)));
typedef unsigned u32x4 __attribute__((ext_vector_type(4)));
typedef unsigned long long u64x2 __attribute__((ext_vector_type(2)));
typedef unsigned short ushort_t;

static constexpr int EMBED = 1024;
static constexpr int NHEAD = 16;
static constexpr int HDIM  = 64;
static constexpr int S_    = 2048;
static constexpr float SCALE_L2E = 0.125f * 1.44269504088896340736f; // (1/sqrt(64))*log2(e)

DEV ushort_t f2bf(float f) {
  unsigned u = __builtin_bit_cast(unsigned, f);
  unsigned r = (u + 0x7fffu + ((u >> 16) & 1u)) >> 16;
  return (ushort_t)r;
}

// async global->LDS, 16B per lane; LDS dest is wave-uniform base + lane*16
#define GLOAD_LDS16(g, l)                                                   \
  __builtin_amdgcn_global_load_lds(                                         \
      (const __attribute__((address_space(1))) unsigned int*)(g),           \
      (__attribute__((address_space(3))) unsigned int*)(l), 16, 0, 0)

// explicit drain of global_load_lds before a publish barrier
#define DRAIN_VM() asm volatile("s_waitcnt vmcnt(0)" ::: "memory")

// ---------------------------------------------------------------------------
// fp32 -> bf16 conversion of x and the four weight matrices
// ---------------------------------------------------------------------------
__global__ __launch_bounds__(256) void convert_kernel(
    const float* __restrict__ x,
    const float* __restrict__ wq, const float* __restrict__ wk,
    const float* __restrict__ wv, const float* __restrict__ wo,
    ushort_t* __restrict__ xb, ushort_t* __restrict__ wqb,
    ushort_t* __restrict__ wkb, ushort_t* __restrict__ wvb,
    ushort_t* __restrict__ wob) {
  size_t i = ((size_t)blockIdx.x * blockDim.x + threadIdx.x) * 4;
  const float* src; ushort_t* dst; size_t off;
  if (i < 4194304u)      { src = x;  dst = xb;  off = i; }
  else if (i < 5242880u) { src = wq; dst = wqb; off = i - 4194304u; }
  else if (i < 6291456u) { src = wk; dst = wkb; off = i - 5242880u; }
  else if (i < 7340032u) { src = wv; dst = wvb; off = i - 6291456u; }
  else                   { src = wo; dst = wob; off = i - 7340032u; }
  float4 v = *(const float4*)(src + off);
  ushort4 o;
  o.x = f2bf(v.x); o.y = f2bf(v.y); o.z = f2bf(v.z); o.w = f2bf(v.w);
  *(ushort4*)(dst + off) = o;
}

// ---------------------------------------------------------------------------
// Merged QKV GEMM, 1-D grid of 768 blocks (R12-green single-buffer m97):
//   bid <256 : Q = xb @ Wq^T  -> [B,H,S,D], (acc+bias)*mask*SCALE_L2E
//   bid <512 : K = xb @ Wk^T  -> [B,H,S,D], (acc+bias)*mask
//   else     : V^T (A=Wv, B=xb) -> [B,H,D,S], acc+bias
// ---------------------------------------------------------------------------
__global__ __launch_bounds__(256) void qkv_kernel(
    const ushort_t* __restrict__ xb, const ushort_t* __restrict__ wqb,
    const ushort_t* __restrict__ wkb, const ushort_t* __restrict__ wvb,
    const float* __restrict__ bq, const float* __restrict__ bk,
    const float* __restrict__ bv, const int* __restrict__ mask,
    ushort_t* __restrict__ qo, ushort_t* __restrict__ ko,
    ushort_t* __restrict__ vto) {
  __shared__ __align__(16) unsigned char ldsA[16384];
  __shared__ __align__(16) unsigned char ldsB[16384];
  __shared__ float maskf[2][128];

  const int bid  = blockIdx.x;
  const int tid  = threadIdx.x;
  const int lane = tid & 63;
  const int w    = tid >> 6;
  const int wm   = (w >> 1) * 64;
  const int wn   = (w & 1) * 64;
  const int rl   = lane & 15;
  const int kg   = lane >> 4;

  int mode, ar0, br0;
  const ushort_t *A, *Bm;
  const float* bias;
  if (bid < 512) {
    mode = bid >> 8;                 // 0=Q, 1=K
    int t = bid & 255;
    ar0 = (t & 31) * 128;            // x rows
    br0 = (t >> 5) * 128;            // weight rows
    A = xb; Bm = mode ? wkb : wqb; bias = mode ? bk : bq;
  } else {
    mode = 2;
    int t = bid - 512;
    ar0 = (t & 7) * 128;             // weight rows
    br0 = (t >> 3) * 128;            // x rows
    A = wvb; Bm = xb; bias = bv;
  }

  if (mode < 2) {
    int hl = tid >> 7, sl = tid & 127;
    int m = ar0 + sl;
    int b = m >> 11, s = m & 2047;
    int h = (br0 >> 6) + hl;
    maskf[hl][sl] = (float)mask[((size_t)b * NHEAD + h) * S_ + s];
  }

  f32x4 acc[4][4];
#pragma unroll
  for (int i = 0; i < 4; ++i)
#pragma unroll
    for (int j = 0; j < 4; ++j) acc[i][j] = f32x4{0.f, 0.f, 0.f, 0.f};

  auto STAGE = [&](int kt) {
    const int k0 = kt * 64;
#pragma unroll
    for (int s = 0; s < 8; ++s) {
      const int basev = s * 256 + w * 64;   // wave-uniform
      const int Lb = basev & 1023;
      const int L = Lb + lane;
      const int row = L >> 3;
      const int gu = (L & 7) ^ (row & 7);
      if (s < 4) {
        GLOAD_LDS16(A + (size_t)(ar0 + row) * EMBED + k0 + gu * 8, &ldsA[Lb * 16]);
      } else {
        GLOAD_LDS16(Bm + (size_t)(br0 + row) * EMBED + k0 + gu * 8, &ldsB[Lb * 16]);
      }
    }
  };

  for (int kt = 0; kt < 16; ++kt) {
    if (kt) __syncthreads();          // all waves done reading previous tile
    STAGE(kt);
    DRAIN_VM();                       // my loads landed
    __syncthreads();                  // everyone's loads landed
#pragma unroll
    for (int kk = 0; kk < 2; ++kk) {
      bf16x8 af[4], bfr[4];
#pragma unroll
      for (int mb = 0; mb < 4; ++mb) {
        const int row = wm + mb * 16 + rl;
        const int off = (kk * 64 + kg * 16) ^ ((row & 7) << 4);
        af[mb] = *(const bf16x8*)(ldsA + row * 128 + off);
      }
#pragma unroll
      for (int nb = 0; nb < 4; ++nb) {
        const int row = wn + nb * 16 + rl;
        const int off = (kk * 64 + kg * 16) ^ ((row & 7) << 4);
        bfr[nb] = *(const bf16x8*)(ldsB + row * 128 + off);
      }
#pragma unroll
      for (int mb = 0; mb < 4; ++mb)
#pragma unroll
        for (int nb = 0; nb < 4; ++nb)
          acc[mb][nb] = __builtin_amdgcn_mfma_f32_16x16x32_bf16(
              af[mb], bfr[nb], acc[mb][nb], 0, 0, 0);
    }
  }

  // epilogue — D layout: row(A idx)=(lane>>4)*4+r, col(B idx)=lane&15
#pragma unroll
  for (int mb = 0; mb < 4; ++mb)
#pragma unroll
    for (int nb = 0; nb < 4; ++nb)
#pragma unroll
      for (int r = 0; r < 4; ++r) {
        int row_l = wm + mb * 16 + kg * 4 + r;
        int col_l = wn + nb * 16 + rl;
        float v = acc[mb][nb][r];
        if (mode < 2) {
          int m = ar0 + row_l, n = br0 + col_l;
          v = (v + bias[n]) * maskf[col_l >> 6][row_l];
          if (mode == 0) v *= SCALE_L2E;
          int b = m >> 11, s = m & 2047, h = n >> 6, d = n & 63;
          ushort_t* o = mode ? ko : qo;
          o[(((size_t)(b * NHEAD + h)) * S_ + s) * HDIM + d] = f2bf(v);
        } else {
          int n = ar0 + row_l, m = br0 + col_l;
          v += bias[n];
          int b = m >> 11, s = m & 2047, h = n >> 6, d = n & 63;
          vto[(((size_t)(b * NHEAD + h)) * HDIM + d) * S_ + s] = f2bf(v);
        }
      }
}

// ---------------------------------------------------------------------------
// O projection GEMM: out[m][n] = aob[m][:] . Wo[n][:] + bo[n]  (fp32 out)
// 128x64 tiles -> grid (32,16) = 512 blocks = 2 blocks/CU: inter-block
// overlap hides the per-K-step staging drains (m114 mechanism).
// ---------------------------------------------------------------------------
__global__ __launch_bounds__(256) void gemm_o_kernel(
    const ushort_t* __restrict__ A, const ushort_t* __restrict__ Bm,
    const float* __restrict__ bias, float* __restrict__ outp) {
  __shared__ __align__(16) unsigned char ldsA[16384];
  __shared__ __align__(16) unsigned char ldsB[8192];

  const int tid  = threadIdx.x;
  const int lane = tid & 63;
  const int w    = tid >> 6;
  const int ar0  = blockIdx.x * 128;
  const int br0  = blockIdx.y * 64;
  const int wm   = (w >> 1) * 64;
  const int wn   = (w & 1) * 32;
  const int rl   = lane & 15;
  const int kg   = lane >> 4;

  f32x4 acc[4][2];
#pragma unroll
  for (int i = 0; i < 4; ++i)
#pragma unroll
    for (int j = 0; j < 2; ++j) acc[i][j] = f32x4{0.f, 0.f, 0.f, 0.f};

  auto STAGE = [&](int kt) {
    const int k0 = kt * 64;
#pragma unroll
    for (int s = 0; s < 6; ++s) {
      if (s < 4) {
        const int Lb = s * 256 + w * 64;      // wave-uniform, 1024 A-units
        const int L = Lb + lane;
        const int row = L >> 3;
        const int gu = (L & 7) ^ (row & 7);
        GLOAD_LDS16(A + (size_t)(ar0 + row) * EMBED + k0 + gu * 8, &ldsA[Lb * 16]);
      } else {
        const int Lb = (s - 4) * 256 + w * 64; // wave-uniform, 512 B-units
        const int L = Lb + lane;
        const int row = L >> 3;
        const int gu = (L & 7) ^ (row & 7);
        GLOAD_LDS16(Bm + (size_t)(br0 + row) * EMBED + k0 + gu * 8, &ldsB[Lb * 16]);
      }
    }
  };

  for (int kt = 0; kt < 16; ++kt) {
    if (kt) __syncthreads();
    STAGE(kt);
    DRAIN_VM();
    __syncthreads();
#pragma unroll
    for (int kk = 0; kk < 2; ++kk) {
      bf16x8 af[4], bfr[2];
#pragma unroll
      for (int mb = 0; mb < 4; ++mb) {
        const int row = wm + mb * 16 + rl;
        const int off = (kk * 64 + kg * 16) ^ ((row & 7) << 4);
        af[mb] = *(const bf16x8*)(ldsA + row * 128 + off);
      }
#pragma unroll
      for (int nb = 0; nb < 2; ++nb) {
        const int row = wn + nb * 16 + rl;
        const int off = (kk * 64 + kg * 16) ^ ((row & 7) << 4);
        bfr[nb] = *(const bf16x8*)(ldsB + row * 128 + off);
      }
#pragma unroll
      for (int mb = 0; mb < 4; ++mb)
#pragma unroll
        for (int nb = 0; nb < 2; ++nb)
          acc[mb][nb] = __builtin_amdgcn_mfma_f32_16x16x32_bf16(
              af[mb], bfr[nb], acc[mb][nb], 0, 0, 0);
    }
  }

#pragma unroll
  for (int mb = 0; mb < 4; ++mb)
#pragma unroll
    for (int nb = 0; nb < 2; ++nb)
#pragma unroll
      for (int r = 0; r < 4; ++r) {
        int m = ar0 + wm + mb * 16 + kg * 4 + r;
        int n = br0 + wn + nb * 16 + rl;
        outp[(size_t)m * EMBED + n] = acc[mb][nb][r] + bias[n];
      }
}

// ---------------------------------------------------------------------------
// Flash attention, swapped-QK^T, fixed-exponent softmax — 2-TILE UNROLL
// (intra-wave ILP) with CONFLICT-FREE P SWIZZLE:
//   write byte = (2*key) ^ ((rl&7)<<4) ^ (rl&8); read compensates via two
//   u64 loads at B+(rl&8) and B+8-(rl&8). SQ_LDS_BANK_CONFLICT = 0.
// 4 KV slots, 2-tiles-ahead prefetch, counted vmcnt; raw s_barrier;
// 8 waves x 16 q; XCD-resident decode; s_setprio around MFMA clusters.
// LDS: K 4x8KB + V 4x8KB + P 8x2KB = 80KB -> 2 blocks/CU.
// ---------------------------------------------------------------------------
__global__ __launch_bounds__(512) void attn_kernel(
    const ushort_t* __restrict__ qp, const ushort_t* __restrict__ kp,
    const ushort_t* __restrict__ vtp, ushort_t* __restrict__ ao) {
  __shared__ __align__(16) unsigned char ldsK[4][8192];
  __shared__ __align__(16) unsigned char ldsV[4][8192];
  __shared__ __align__(16) unsigned char ldsP[8][2048];

  const int bid  = blockIdx.x;
  const int bh   = (bid & 7) * 4 + (bid >> 7); // XCD-resident head slice
  const int qt   = (bid >> 3) & 15;
  const int tid  = threadIdx.x;
  const int lane = tid & 63;
  const int w    = tid >> 6;                  // 0..7
  const int q0   = qt * 128 + w * 16;         // wave's q base (16 rows)
  const int rl   = lane & 15;
  const int kg   = lane >> 4;
  const int pswz = (rl & 7) << 4;
  const int rl8  = rl & 8;                    // P half-swap bit

  const bf16x8 ones = __builtin_bit_cast(bf16x8,
      u32x4{0x3F803F80u, 0x3F803F80u, 0x3F803F80u, 0x3F803F80u});

  // Q fragments (B-operand): lane (rl,kg) holds Q[q=rl][d=kk*32+kg*8..+8]
  bf16x8 qa[2];
#pragma unroll
  for (int kk = 0; kk < 2; ++kk)
    qa[kk] = *(const bf16x8*)(qp + ((size_t)bh * S_ + q0 + rl) * HDIM +
                              kk * 32 + kg * 8);

  f32x4 o_acc[4];
  f32x4 o_l = f32x4{0.f, 0.f, 0.f, 0.f};
#pragma unroll
  for (int nb = 0; nb < 4; ++nb) o_acc[nb] = f32x4{0.f, 0.f, 0.f, 0.f};

  unsigned char* pb = ldsP[w];

  // stage KV tile kt into slot: 512 K units + 512 V units, 2 insts/thread
  auto STAGE = [&](int kt, int slot) {
#pragma unroll
    for (int s = 0; s < 2; ++s) {
      const int Lb = w * 64;                  // wave-uniform, 8 waves x 64
      const int L = Lb + lane;
      const int row = L >> 3;
      const int gu = (L & 7) ^ (row & 7);
      if (s == 0) {
        GLOAD_LDS16(kp + ((size_t)bh * S_ + (size_t)kt * 64 + row) * HDIM + gu * 8,
                    &ldsK[slot][L * 16]);
      } else {
        GLOAD_LDS16(vtp + ((size_t)bh * HDIM + row) * S_ + (size_t)kt * 64 + gu * 8,
                    &ldsV[slot][L * 16]);
      }
    }
  };

  // per-tile pieces (static indexing; called twice per iteration)
  auto QK = [&](int slot, f32x4 sa[4]) {
#pragma unroll
    for (int nb = 0; nb < 4; ++nb) {
      const int row = nb * 16 + rl;
#pragma unroll
      for (int kk = 0; kk < 2; ++kk) {
        bf16x8 kf = *(const bf16x8*)(ldsK[slot] + row * 128 +
                                     ((kk * 64 + kg * 16) ^ ((row & 7) << 4)));
        sa[nb] = __builtin_amdgcn_mfma_f32_16x16x32_bf16(kf, qa[kk], sa[nb], 0, 0, 0);
      }
    }
  };
  auto SMW = [&](const f32x4 sa[4]) {          // exp2 -> bf16 -> P writes
#pragma unroll
    for (int nb = 0; nb < 4; ++nb) {
      bf16x4 pk4;
#pragma unroll
      for (int r = 0; r < 4; ++r)
        pk4[r] = (__bf16)__builtin_amdgcn_exp2f(sa[nb][r]);
      *(bf16x4*)(pb + rl * 128 + ((nb * 32 + kg * 8) ^ pswz ^ rl8)) = pk4;
    }
  };
  auto PVL = [&](int slot) {                   // P read, l, PV
    bf16x8 pa[2];
#pragma unroll
    for (int kk = 0; kk < 2; ++kk) {
      const unsigned char* base = pb + rl * 128 + ((kk * 64 + kg * 16) ^ pswz);
      unsigned long long lo = *(const unsigned long long*)(base + rl8);
      unsigned long long hi = *(const unsigned long long*)(base + 8 - rl8);
      pa[kk] = __builtin_bit_cast(bf16x8, u64x2{lo, hi});
    }
    o_l = __builtin_amdgcn_mfma_f32_16x16x32_bf16(pa[0], ones, o_l, 0, 0, 0);
    o_l = __builtin_amdgcn_mfma_f32_16x16x32_bf16(pa[1], ones, o_l, 0, 0, 0);
#pragma unroll
    for (int nb = 0; nb < 4; ++nb) {
      const int row = nb * 16 + rl;
#pragma unroll
      for (int kk = 0; kk < 2; ++kk) {
        bf16x8 vb = *(const bf16x8*)(ldsV[slot] + row * 128 +
                                     ((kk * 64 + kg * 16) ^ ((row & 7) << 4)));
        o_acc[nb] = __builtin_amdgcn_mfma_f32_16x16x32_bf16(pa[kk], vb, o_acc[nb], 0, 0, 0);
      }
    }
  };

  STAGE(0, 0); STAGE(1, 1); STAGE(2, 2); STAGE(3, 3);
  asm volatile("s_waitcnt vmcnt(4) lgkmcnt(0)" ::: "memory"); // tiles 0,1 landed
  __builtin_amdgcn_s_barrier();

  for (int kt = 0; kt < 32; kt += 2) {
    const int s0 = kt & 3, s1 = (kt + 1) & 3;

    f32x4 saA[4], saB[4];
#pragma unroll
    for (int nb = 0; nb < 4; ++nb) { saA[nb] = f32x4{0.f,0.f,0.f,0.f}; saB[nb] = f32x4{0.f,0.f,0.f,0.f}; }

    __builtin_amdgcn_s_setprio(1);
    QK(s0, saA);
    QK(s1, saB);
    __builtin_amdgcn_s_setprio(0);

    SMW(saA);
    asm volatile("s_waitcnt lgkmcnt(0)" ::: "memory");
    __builtin_amdgcn_sched_barrier(0);

    // region: PV_A MFMAs interleave with SM_B VALU (independent, same wave)
    __builtin_amdgcn_s_setprio(1);
    PVL(s0);
    __builtin_amdgcn_s_setprio(0);
    SMW(saB);
    asm volatile("s_waitcnt lgkmcnt(0)" ::: "memory");
    __builtin_amdgcn_sched_barrier(0);

    __builtin_amdgcn_s_setprio(1);
    PVL(s1);
    __builtin_amdgcn_s_setprio(0);

    // publish: all waves done reading slots s0,s1; restage them 2 ahead
    __builtin_amdgcn_s_barrier();
    if (kt + 4 < 32) {
      STAGE(kt + 4, s0); STAGE(kt + 5, s1);
      asm volatile("s_waitcnt vmcnt(4) lgkmcnt(0)" ::: "memory"); // kt+2,kt+3 landed
    } else {
      asm volatile("s_waitcnt vmcnt(0) lgkmcnt(0)" ::: "memory");
    }
    __builtin_amdgcn_s_barrier();
  }

  // epilogue: O[q=kg*4+r][d=nb*16+rl] / l[q]; o_l aligned with o_acc
  const int b = bh >> 4, h = bh & 15;
#pragma unroll
  for (int r = 0; r < 4; ++r) {
    float linv = 1.0f / o_l[r];
    const int row = q0 + kg * 4 + r;
#pragma unroll
    for (int nb = 0; nb < 4; ++nb) {
      float v = o_acc[nb][r] * linv;
      ao[((size_t)b * S_ + row) * EMBED + h * HDIM + nb * 16 + rl] = f2bf(v);
    }
  }
}

// ---------------------------------------------------------------------------
extern "C" void kernel_launch(void* const* d_in, const int* in_sizes, int n_in,
                              void* d_out, int out_size, void* d_ws, size_t ws_size,
                              hipStream_t stream) {
  const float* x    = (const float*)d_in[0];
  const int*   mask = (const int*)d_in[1];
  const float* Wq   = (const float*)d_in[2];
  const float* bq   = (const float*)d_in[3];
  const float* Wk   = (const float*)d_in[4];
  const float* bk   = (const float*)d_in[5];
  const float* Wv   = (const float*)d_in[6];
  const float* bv   = (const float*)d_in[7];
  const float* Wo   = (const float*)d_in[8];
  const float* bo   = (const float*)d_in[9];

  char* ws = (char*)d_ws;
  ushort_t* xb  = (ushort_t*)(ws);
  ushort_t* wqb = (ushort_t*)(ws + 8388608);
  ushort_t* wkb = (ushort_t*)(ws + 10485760);
  ushort_t* wvb = (ushort_t*)(ws + 12582912);
  ushort_t* wob = (ushort_t*)(ws + 14680064);
  ushort_t* qb  = (ushort_t*)(ws + 16777216);
  ushort_t* kb  = (ushort_t*)(ws + 25165824);
  ushort_t* vtb = (ushort_t*)(ws + 33554432);
  ushort_t* aob = (ushort_t*)(ws + 41943040);

  hipLaunchKernelGGL(convert_kernel, dim3(8192), dim3(256), 0, stream,
                     x, Wq, Wk, Wv, Wo, xb, wqb, wkb, wvb, wob);
  hipLaunchKernelGGL(qkv_kernel, dim3(768), dim3(256), 0, stream,
                     xb, wqb, wkb, wvb, bq, bk, bv, mask, qb, kb, vtb);
  hipLaunchKernelGGL(attn_kernel, dim3(512), dim3(512), 0, stream,
                     qb, kb, vtb, aob);
  hipLaunchKernelGGL(gemm_o_kernel, dim3(32, 16), dim3(256), 0, stream,
                     aob, wob, bo, (float*)d_out);
}